// Round 11
// baseline (822.951 us; speedup 1.0000x reference)
//
#include <hip/hip_runtime.h>
#include <hip/hip_bf16.h>

typedef __hip_bfloat16 bf16;
typedef __attribute__((ext_vector_type(8))) short short8;
typedef __attribute__((ext_vector_type(4))) short short4v;
typedef __attribute__((ext_vector_type(4))) float f32x4;

__device__ __forceinline__ short f2b(float v)
{
    union { bf16 b; short s; } u;
    u.b = __float2bfloat16(v);
    return u.s;
}
__device__ __forceinline__ float b2f(short s)
{
    union { short s; bf16 b; } u;
    u.s = s;
    return __bfloat162float(u.b);
}
__device__ __forceinline__ void splt(float v, short& hi, short& lo)
{
    hi = f2b(v);
    lo = f2b(v - b2f(hi));
}
__device__ __forceinline__ int bsw(int row, int g)
{
    return row * 40 + (((g + (row >> 3)) & 3) << 3);
}

// ---------------------------------------------------------------------------
// Dtype detector (validated r2): flag=1 -> fp32 storage, 0 -> bf16.
// ---------------------------------------------------------------------------
__global__ void detect_k(const unsigned short* __restrict__ p, int* __restrict__ flag)
{
    __shared__ int cnt;
    if (threadIdx.x == 0) cnt = 0;
    __syncthreads();
    int bad = 0;
    for (int i = threadIdx.x; i < 4096; i += 256) {
        unsigned short u = p[2 * i];
        int e = (u >> 7) & 0xFF;
        if (e != 0 && (e < 100 || e > 140)) bad++;
    }
    atomicAdd(&cnt, bad);
    __syncthreads();
    if (threadIdx.x == 0) *flag = (cnt > 1024) ? 1 : 0;
}

// ---------------------------------------------------------------------------
// Fused ingest (validated r5)
// ---------------------------------------------------------------------------
#define NSEG 24
struct IArgs {
    const void* src[NSEG];
    float* dst[NSEG];
    long start[NSEG + 1];
};

__global__ void ingest_all_k(IArgs a, const int* __restrict__ flag)
{
    long i = (long)blockIdx.x * 256 + threadIdx.x;
    if (i >= a.start[NSEG]) return;
    int s = 0;
#pragma unroll
    for (int j = 1; j < NSEG; j++) s += (i >= a.start[j]) ? 1 : 0;
    long idx = i - a.start[s];
    float v;
    if (*flag) v = ((const float*)a.src[s])[idx];
    else       v = __bfloat162float(((const bf16*)a.src[s])[idx]);
    a.dst[s][idx] = v;
}

// C[b][m][n] = bias[m] (or 0).  total = B*MN.
__global__ void fill_k(float* __restrict__ C, const float* __restrict__ bias,
                       long MN, int Nn, long total)
{
    long i = (long)blockIdx.x * 256 + threadIdx.x;
    if (i >= total) return;
    float v = 0.f;
    if (bias) {
        long r = i % MN;
        v = bias[(int)(r / Nn)];
    }
    C[i] = v;
}

// Tiled transpose: X[b][c][n] -> XT[b][n][c].  C=256. grid (N/32, 8, B), blk (32,8)
__global__ void tr_k(const float* __restrict__ X, float* __restrict__ XT, int N)
{
    __shared__ float t[32][33];
    int b = blockIdx.z, n0 = blockIdx.x * 32, c0 = blockIdx.y * 32;
    const float* Xb = X + (long)b * 256 * N;
    float* Tb = XT + (long)b * 256 * N;
    int tx = threadIdx.x, ty = threadIdx.y;
#pragma unroll
    for (int i = 0; i < 4; i++)
        t[ty + 8 * i][tx] = Xb[(long)(c0 + ty + 8 * i) * N + n0 + tx];
    __syncthreads();
#pragma unroll
    for (int i = 0; i < 4; i++)
        Tb[(long)(n0 + ty + 8 * i) * 256 + c0 + tx] = t[tx][ty + 8 * i];
}

// ---------------------------------------------------------------------------
// MFMA bf16 GEMM (validated r8/r9) — non-DCN ops.
// ---------------------------------------------------------------------------
template <bool TRA, int BMODE, bool ACCUM, bool BIAS, int PREC, int KSPLIT>
__launch_bounds__(256)
__global__ void mgemm(const float* __restrict__ A, int lda, int ksA, long sA,
                      const void* __restrict__ Bsrc, int ldb, long sB,
                      float* __restrict__ C, int ldc, long sC,
                      const float* __restrict__ bias,
                      int M, int N, int K, int H, int wsh)
{
    __shared__ short As[PREC * 2560];
    __shared__ short Bs[PREC * 2560];

    const int bz = blockIdx.z;
    const float* Ab = A + (long)bz * sA;
    float* Cb = C + (long)bz * sC;
    const int mt = blockIdx.y / KSPLIT, ch = blockIdx.y % KSPLIT;
    const int m0 = mt * 64, n0 = blockIdx.x * 64;
    const int kchunk = K / KSPLIT;
    const int kbeg = ch * kchunk, kend = kbeg + kchunk;
    const int tid = threadIdx.x;

    f32x4 acc[2][2];
#pragma unroll
    for (int i = 0; i < 2; i++)
#pragma unroll
        for (int j = 0; j < 2; j++) acc[i][j] = (f32x4){0.f, 0.f, 0.f, 0.f};

    const int lane = tid & 63, wv = tid >> 6;
    const int moff = (wv & 1) * 32, noff = (wv >> 1) * 32;
    const int lr = lane & 15, lq = lane >> 4;
    const int mm = tid >> 2, kk0 = (tid & 3) * 8;
    const int nn = tid & 63, kg = tid >> 6;

    for (int k0 = kbeg; k0 < kend; k0 += 32) {
        // ---- stage A ----
        {
            float vv[8];
            if (m0 + mm < M) {
                if (!TRA) {
                    if (ksA == 1) {
                        const float4* s4 = (const float4*)(Ab + (long)(m0 + mm) * lda + k0 + kk0);
                        float4 v0 = s4[0], v1 = s4[1];
                        vv[0] = v0.x; vv[1] = v0.y; vv[2] = v0.z; vv[3] = v0.w;
                        vv[4] = v1.x; vv[5] = v1.y; vv[6] = v1.z; vv[7] = v1.w;
                    } else {
                        const float* s = Ab + (long)(m0 + mm) * lda + (long)(k0 + kk0) * ksA;
#pragma unroll
                        for (int j = 0; j < 8; j++) vv[j] = s[(long)j * ksA];
                    }
                } else {
#pragma unroll
                    for (int j = 0; j < 8; j++)
                        vv[j] = Ab[(long)(k0 + kk0 + j) * lda + m0 + mm];
                }
            } else {
#pragma unroll
                for (int j = 0; j < 8; j++) vv[j] = 0.f;
            }
            short8 hi, lo;
#pragma unroll
            for (int j = 0; j < 8; j++) { short h, l; splt(vv[j], h, l); hi[j] = h; lo[j] = l; }
            *(short8*)&As[mm * 40 + kk0] = hi;
            if (PREC == 2) *(short8*)&As[2560 + mm * 40 + kk0] = lo;
        }

        // ---- stage B ----
        if (BMODE == 1) {
            const float4* s4 = (const float4*)((const float*)Bsrc + (long)bz * sB +
                                               (long)(n0 + mm) * ldb + k0 + kk0);
            float4 v0 = s4[0], v1 = s4[1];
            float vv[8] = {v0.x, v0.y, v0.z, v0.w, v1.x, v1.y, v1.z, v1.w};
            short8 hi, lo;
#pragma unroll
            for (int j = 0; j < 8; j++) { short h, l; splt(vv[j], h, l); hi[j] = h; lo[j] = l; }
            int o = bsw(mm, tid & 3);
            *(short8*)&Bs[o] = hi;
            if (PREC == 2) *(short8*)&Bs[2560 + o] = lo;
        } else {
            float vv[8];
            if (BMODE == 0) {
#pragma unroll
                for (int j = 0; j < 8; j++)
                    vv[j] = ((const float*)Bsrc)[(long)bz * sB + (long)(k0 + kg * 8 + j) * ldb + n0 + nn];
            } else {  // BMODE 3: im2col
                int W = 1 << wsh;
                int n = n0 + nn;
                int hbase = n >> wsh, wbase = n & (W - 1);
#pragma unroll
                for (int j = 0; j < 8; j++) {
                    int kc = k0 + kg * 8 + j;
                    int c = kc / 9, tap = kc - 9 * c;
                    int h = hbase + tap / 3 - 1, w = wbase + tap % 3 - 1;
                    vv[j] = (h >= 0 && h < H && w >= 0 && w < W)
                          ? ((const float*)Bsrc)[(long)bz * sB + (long)c * ldb + (h << wsh) + w]
                          : 0.f;
                }
            }
            short8 hi, lo;
#pragma unroll
            for (int j = 0; j < 8; j++) { short h, l; splt(vv[j], h, l); hi[j] = h; lo[j] = l; }
            int o = bsw(nn, kg);
            *(short8*)&Bs[o] = hi;
            if (PREC == 2) *(short8*)&Bs[2560 + o] = lo;
        }
        __syncthreads();

        // ---- compute ----
        int rb0 = noff + lr, rb1 = noff + 16 + lr;
        short8 a0h = *(short8*)&As[(moff + lr) * 40 + lq * 8];
        short8 a1h = *(short8*)&As[(moff + 16 + lr) * 40 + lq * 8];
        short8 b0h = *(short8*)&Bs[bsw(rb0, lq)];
        short8 b1h = *(short8*)&Bs[bsw(rb1, lq)];
        acc[0][0] = __builtin_amdgcn_mfma_f32_16x16x32_bf16(a0h, b0h, acc[0][0], 0, 0, 0);
        acc[0][1] = __builtin_amdgcn_mfma_f32_16x16x32_bf16(a0h, b1h, acc[0][1], 0, 0, 0);
        acc[1][0] = __builtin_amdgcn_mfma_f32_16x16x32_bf16(a1h, b0h, acc[1][0], 0, 0, 0);
        acc[1][1] = __builtin_amdgcn_mfma_f32_16x16x32_bf16(a1h, b1h, acc[1][1], 0, 0, 0);
        if (PREC == 2) {
            short8 a0l = *(short8*)&As[2560 + (moff + lr) * 40 + lq * 8];
            short8 a1l = *(short8*)&As[2560 + (moff + 16 + lr) * 40 + lq * 8];
            short8 b0l = *(short8*)&Bs[2560 + bsw(rb0, lq)];
            short8 b1l = *(short8*)&Bs[2560 + bsw(rb1, lq)];
            acc[0][0] = __builtin_amdgcn_mfma_f32_16x16x32_bf16(a0h, b0l, acc[0][0], 0, 0, 0);
            acc[0][1] = __builtin_amdgcn_mfma_f32_16x16x32_bf16(a0h, b1l, acc[0][1], 0, 0, 0);
            acc[1][0] = __builtin_amdgcn_mfma_f32_16x16x32_bf16(a1h, b0l, acc[1][0], 0, 0, 0);
            acc[1][1] = __builtin_amdgcn_mfma_f32_16x16x32_bf16(a1h, b1l, acc[1][1], 0, 0, 0);
            acc[0][0] = __builtin_amdgcn_mfma_f32_16x16x32_bf16(a0l, b0h, acc[0][0], 0, 0, 0);
            acc[0][1] = __builtin_amdgcn_mfma_f32_16x16x32_bf16(a0l, b1h, acc[0][1], 0, 0, 0);
            acc[1][0] = __builtin_amdgcn_mfma_f32_16x16x32_bf16(a1l, b0h, acc[1][0], 0, 0, 0);
            acc[1][1] = __builtin_amdgcn_mfma_f32_16x16x32_bf16(a1l, b1h, acc[1][1], 0, 0, 0);
        }
        __syncthreads();
    }

    // ---- epilogue ----
#pragma unroll
    for (int mi = 0; mi < 2; mi++)
#pragma unroll
        for (int ni = 0; ni < 2; ni++) {
            int col = n0 + noff + ni * 16 + lr;
#pragma unroll
            for (int r = 0; r < 4; r++) {
                int row = m0 + moff + mi * 16 + lq * 4 + r;
                if (row < M) {
                    long o = (long)row * ldc + col;
                    float v = acc[mi][ni][r];
                    if (KSPLIT > 1) {
                        atomicAdd(&Cb[o], v);
                    } else {
                        if (BIAS) v += bias[row];
                        if (ACCUM) v += Cb[o];
                        Cb[o] = v;
                    }
                }
            }
        }
}

// ---------------------------------------------------------------------------
// DCN bilinear corner tables
// ---------------------------------------------------------------------------
__global__ void dcnw_k(const float* __restrict__ OO, float4* __restrict__ Tw,
                       int4* __restrict__ Ta, int N, int H, int W)
{
    long idx = (long)blockIdx.x * 256 + threadIdx.x;
    if (idx >= (long)16 * 9 * N) return;
    int b = (int)(idx / (9 * N));
    int r = (int)(idx % (9 * N));
    int tap = r / N, p = r % N;
    int h = p / W, w = p % W;
    const float* oob = OO + (long)b * 27 * N;
    float oy = oob[(2 * tap) * N + p];
    float ox = oob[(2 * tap + 1) * N + p];
    float mz = oob[(18 + tap) * N + p];
    float mask = 1.f / (1.f + expf(-mz));
    float y = (float)(h - 1 + tap / 3) + oy;
    float x = (float)(w - 1 + tap % 3) + ox;
    float y0 = floorf(y), x0 = floorf(x);
    float wy = y - y0, wx = x - x0;
    float ys[2] = {y0, y0 + 1.f};
    float xs[2] = {x0, x0 + 1.f};
    float wys[2] = {1.f - wy, wy};
    float wxs[2] = {1.f - wx, wx};
    float wv[4]; int av[4];
#pragma unroll
    for (int iy = 0; iy < 2; iy++)
#pragma unroll
        for (int ix = 0; ix < 2; ix++) {
            float yy = ys[iy], xx = xs[ix];
            bool valid = (yy >= 0.f) && (yy <= (float)(H - 1)) &&
                         (xx >= 0.f) && (xx <= (float)(W - 1));
            wv[iy * 2 + ix] = valid ? wys[iy] * wxs[ix] * mask : 0.f;
            int yc = (int)fminf(fmaxf(yy, 0.f), (float)(H - 1));
            int xc = (int)fminf(fmaxf(xx, 0.f), (float)(W - 1));
            av[iy * 2 + ix] = yc * W + xc;
        }
    Tw[idx] = (float4){wv[0], wv[1], wv[2], wv[3]};
    Ta[idx] = (int4){av[0], av[1], av[2], av[3]};
}

// ---------------------------------------------------------------------------
// DCN weight prepack (r19, validated): SINGLE-PLANE bf16,
// Wh[o][tap*256 + c], row stride 2304 shorts.
// ---------------------------------------------------------------------------
__global__ void wre4_k(const float* __restrict__ W, short* __restrict__ Wh)
{
    long idx = (long)blockIdx.x * 256 + threadIdx.x;
    if (idx >= 2304L * 256) return;
    int o = (int)(idx / 2304);
    int k = (int)(idx % 2304);
    int tap = k >> 8, c = k & 255;
    Wh[(long)o * 2304 + tap * 256 + c] = f2b(W[((long)o * 256 + c) * 9 + tap]);
}

// ---------------------------------------------------------------------------
// samp_k (r18, validated): WAVE-COALESCED gather.  4-lane group owns one n;
// lane cc2 reads float4 index q*4+cc2 of each corner row -> one contiguous
// 64B line per group per instruction.  Grid: (N/64, 9, B), blk 256.
// ---------------------------------------------------------------------------
__global__ void samp_k(const float4* __restrict__ Tw, const int4* __restrict__ Ta,
                       const float* __restrict__ XT, short* __restrict__ Si,
                       int N, int NRND)
{
    int tid = threadIdx.x;
    int g = tid >> 2, cc2 = tid & 3;
    int tap = blockIdx.y, b = blockIdx.z;
    int n = blockIdx.x * 64 + g;
    long ti = ((long)(b * 9 + tap)) * N + n;
    float4 w4 = Tw[ti];
    int4 a4 = Ta[ti];
    const float* Xb = XT + (long)b * 256 * N;
    const float4* r0 = (const float4*)(Xb + (long)a4.x * 256);
    const float4* r1 = (const float4*)(Xb + (long)a4.y * 256);
    const float4* r2 = (const float4*)(Xb + (long)a4.z * 256);
    const float4* r3 = (const float4*)(Xb + (long)a4.w * 256);
    long so = ((long)b * NRND + n) * 2304 + tap * 256;
    short4v out[16];
#pragma unroll
    for (int q = 0; q < 16; q++) {
        int i = q * 4 + cc2;
        float4 p = r0[i], qv = r1[i], s = r2[i], t = r3[i];
        out[q][0] = f2b(w4.x * p.x + w4.y * qv.x + w4.z * s.x + w4.w * t.x);
        out[q][1] = f2b(w4.x * p.y + w4.y * qv.y + w4.z * s.y + w4.w * t.y);
        out[q][2] = f2b(w4.x * p.z + w4.y * qv.z + w4.z * s.z + w4.w * t.z);
        out[q][3] = f2b(w4.x * p.w + w4.y * qv.w + w4.z * s.w + w4.w * t.w);
    }
#pragma unroll
    for (int q = 0; q < 16; q++)
        *(short4v*)&Si[so + q * 16 + cc2 * 4] = out[q];
}

// ---------------------------------------------------------------------------
// Deformable conv v10 (dcn9, r20): FUSED template+search in one 1280-block
// dispatch; 4 waves/SIMD via __launch_bounds__(256,4) + 32-bit offsets +
// unroll 1 (r10 post-mortem: 168 regs/wave -> 3 blocks/CU -> 1024 blocks ran
// as 768+256 with a 1/3-fill tail, plus a separate 256-block template
// dispatch at ~8%% machine fill).  Per-block work is identical across both
// halves (18 kt x 16 MFMA/wave).  Wave-split K + LDS tree + direct store.
// ---------------------------------------------------------------------------
__launch_bounds__(256, 4)
__global__ void dcn9_k(const short* __restrict__ Wh_s, const short* __restrict__ Si_s,
                       const short* __restrict__ Wh_t, const short* __restrict__ Si_t,
                       const float* __restrict__ bias_s, const float* __restrict__ bias_t,
                       float* __restrict__ Cs, float* __restrict__ Ct)
{
    __shared__ float red[8192];               // 2 slots x 64 fidx x 64 lanes

    int bid = blockIdx.x;
    const short* Wh; const short* Si; const float* bias; float* Cb;
    int N, mt, nt;
    if (bid < 1024) {                         // search: 16bz x 4mt x 16nt
        int bz = bid >> 6, t = bid & 63;
        mt = t >> 4; nt = t & 15;
        Wh = Wh_s; Si = Si_s + (long)bz * 1024 * 2304;
        bias = bias_s; Cb = Cs + (long)bz * 256 * 1024; N = 1024;
    } else {                                  // template: 16bz x 4mt x 4nt
        int r = bid - 1024;
        int bz = r >> 4, t = r & 15;
        mt = t >> 2; nt = t & 3;
        Wh = Wh_t; Si = Si_t + (long)bz * 256 * 2304;
        bias = bias_t; Cb = Ct + (long)bz * 256 * 256; N = 256;
    }
    const int m0 = mt * 64, n0 = nt * 64;

    const int tid = threadIdx.x;
    const int lane = tid & 63, wv = tid >> 6;
    const int lr = lane & 15, lq = lane >> 4;

    int aoff[4], boff[4];
#pragma unroll
    for (int mi = 0; mi < 4; mi++)
        aoff[mi] = (m0 + mi * 16 + lr) * 2304 + lq * 8;
#pragma unroll
    for (int ni = 0; ni < 4; ni++)
        boff[ni] = (n0 + ni * 16 + lr) * 2304 + lq * 8;

    f32x4 acc[4][4];
#pragma unroll
    for (int i = 0; i < 4; i++)
#pragma unroll
        for (int j = 0; j < 4; j++) acc[i][j] = (f32x4){0.f, 0.f, 0.f, 0.f};

    // ---- main loop: this wave's 18-kt K-chunk ----
    const int kbeg = wv * 18;
#pragma unroll 1
    for (int kt = kbeg; kt < kbeg + 18; kt++) {
        int koff = (kt >> 3) * 256 + (kt & 7) * 32;
        short8 ah[4], bh[4];
#pragma unroll
        for (int ni = 0; ni < 4; ni++)
            bh[ni] = *(const short8*)&Si[boff[ni] + koff];
#pragma unroll
        for (int mi = 0; mi < 4; mi++)
            ah[mi] = *(const short8*)&Wh[aoff[mi] + koff];
#pragma unroll
        for (int mi = 0; mi < 4; mi++)
#pragma unroll
            for (int ni = 0; ni < 4; ni++)
                acc[mi][ni] = __builtin_amdgcn_mfma_f32_16x16x32_bf16(ah[mi], bh[ni], acc[mi][ni], 0, 0, 0);
    }

    // ---- LDS tree reduction (lane-stride-4B layout: conflict-free b32) ----
    if (wv == 1 || wv == 3) {
        float* rp = &red[(wv == 1 ? 0 : 4096) + lane];
#pragma unroll
        for (int mi = 0; mi < 4; mi++)
#pragma unroll
            for (int ni = 0; ni < 4; ni++)
#pragma unroll
                for (int r2 = 0; r2 < 4; r2++)
                    rp[(mi * 16 + ni * 4 + r2) << 6] = acc[mi][ni][r2];
    }
    __syncthreads();
    if (wv == 0) {
        const float* rp = &red[lane];
#pragma unroll
        for (int mi = 0; mi < 4; mi++)
#pragma unroll
            for (int ni = 0; ni < 4; ni++)
#pragma unroll
                for (int r2 = 0; r2 < 4; r2++)
                    acc[mi][ni][r2] += rp[(mi * 16 + ni * 4 + r2) << 6];
    } else if (wv == 2) {
        float* rp = &red[4096 + lane];
#pragma unroll
        for (int mi = 0; mi < 4; mi++)
#pragma unroll
            for (int ni = 0; ni < 4; ni++)
#pragma unroll
                for (int r2 = 0; r2 < 4; r2++) {
                    int o = (mi * 16 + ni * 4 + r2) << 6;
                    float v = acc[mi][ni][r2] + rp[o];
                    rp[o] = v;
                }
    }
    __syncthreads();
    if (wv == 0) {
        const float* rp = &red[4096 + lane];
#pragma unroll
        for (int mi = 0; mi < 4; mi++)
#pragma unroll
            for (int ni = 0; ni < 4; ni++) {
                int col = n0 + ni * 16 + lr;
#pragma unroll
                for (int r2 = 0; r2 < 4; r2++) {
                    int row = m0 + mi * 16 + lq * 4 + r2;
                    float v = acc[mi][ni][r2] + rp[(mi * 16 + ni * 4 + r2) << 6];
                    Cb[(long)row * N + col] = v + bias[row];
                }
            }
    }
}

// Softmax over batch axis (16)
__global__ void softmax_b_k(float* __restrict__ att, long NN)
{
    long idx = (long)blockIdx.x * 256 + threadIdx.x;
    if (idx >= NN) return;
    float r[16];
    float mx = -1e30f;
#pragma unroll
    for (int b = 0; b < 16; b++) {
        r[b] = att[(long)b * NN + idx];
        mx = fmaxf(mx, r[b]);
    }
    float s = 0.f;
#pragma unroll
    for (int b = 0; b < 16; b++) { r[b] = expf(r[b] - mx); s += r[b]; }
    float inv = 1.f / s;
#pragma unroll
    for (int b = 0; b < 16; b++) att[(long)b * NN + idx] = r[b] * inv;
}

// M[b][c][d] = softmax_c(gram_t) + softmax_c(gram_s)
__global__ void gram_sm_k(const float* __restrict__ gt, const float* __restrict__ gs,
                          float* __restrict__ Mo)
{
    int b = blockIdx.x;
    int d = blockIdx.y * 64 + threadIdx.x;
    const float* gtb = gt + (long)b * 65536;
    const float* gsb = gs + (long)b * 65536;
    float* mb = Mo + (long)b * 65536;
    float mt = -1e30f, ms = -1e30f;
    for (int c = 0; c < 256; c++) {
        mt = fmaxf(mt, gtb[c * 256 + d]);
        ms = fmaxf(ms, gsb[c * 256 + d]);
    }
    float st = 0.f, ss = 0.f;
    for (int c = 0; c < 256; c++) {
        st += expf(gtb[c * 256 + d] - mt);
        ss += expf(gsb[c * 256 + d] - ms);
    }
    float it = 1.f / st, is = 1.f / ss;
    for (int c = 0; c < 256; c++)
        mb[c * 256 + d] = expf(gtb[c * 256 + d] - mt) * it +
                          expf(gsb[c * 256 + d] - ms) * is;
}

__global__ void cast_out_k(const float* __restrict__ t, const float* __restrict__ s,
                           void* __restrict__ out, long nt, long ntot,
                           const int* __restrict__ flag)
{
    long idx = (long)blockIdx.x * 256 + threadIdx.x;
    if (idx >= ntot) return;
    float v = (idx < nt) ? t[idx] : s[idx - nt];
    if (*flag) ((float*)out)[idx] = v;
    else       ((bf16*)out)[idx] = __float2bfloat16(v);
}

// ---------------------------------------------------------------------------
extern "C" void kernel_launch(void* const* d_in, const int* in_sizes, int n_in,
                              void* d_out, int out_size, void* d_ws, size_t ws_size,
                              hipStream_t stream)
{
    const int B = 16, C = 256;
    const int Nt = 256, Ns = 1024;
    const long sXt = (long)C * Nt, sXs = (long)C * Ns;
    dim3 blk(256);

    float* ws = (float*)d_ws;
    int* flag = (int*)d_ws;
    long off = 16;
    auto alloc = [&](long n) { float* p = ws + off; off += n; return p; };

    float* xt32     = alloc((long)B * C * Nt);
    float* xs32     = alloc((long)B * C * Ns);   // -> out_s_f32
    float* Wf       = alloc(1470464);
    float* q_t      = alloc((long)B * 32 * Nt);
    float* k_t      = alloc((long)B * 32 * Nt);
    float* v_t      = alloc((long)B * C * Nt);
    float* q_s      = alloc((long)B * 32 * Ns);
    float* k_s      = alloc((long)B * 32 * Ns);
    float* v_s      = alloc((long)B * C * Ns);   // -> DCN prep region
    float* gram_t   = alloc((long)B * C * C);    // -> out_t_f32
    float* gram_s   = alloc((long)B * C * C);
    float* Mc       = alloc((long)B * C * C);
    float* att_t    = alloc((long)B * Nt * Nt);  // xtT early / atT late
    float* att_slab = alloc((long)B * Ns * 256); // xsT early / asrT late
    float* at       = alloc((long)B * C * Nt);   // -> Si_t region late
    float* asr      = alloc((long)B * C * Ns);   // -> Si_t region late
    float* oo_t     = alloc((long)B * 27 * Nt);
    float* oo_s     = alloc((long)B * 27 * Ns);
    // Single-plane S: search NRND=1024 -> 16*1024*2304 shorts = 18.87M floats.
    float* Si_f     = alloc(18874368);
    short* Si = (short*)Si_f;

    float* out_t_f32 = gram_t;
    float* out_s_f32 = xs32;
    float* xtT       = att_t;
    float* xsT       = att_slab;
    float* atT       = att_t;     // reuse after attention phases complete
    float* asrT      = att_slab;  // reuse after attention phases complete
    // Template Si lives in the dead at+asr region (needs 4.72M floats < 5.24M).
    short* Si_t = (short*)at;
    short* Wi_t = (short*)v_s;                   // 589824 shorts each (hi-only)
    short* Wi_s = (short*)v_s + 589824;
    float* tb   = v_s + 1179648;
    float4* Tw_t = (float4*)tb;
    int4*   Ta_t = (int4*)(tb + 147456);
    float4* Tw_s = (float4*)(tb + 2 * 147456);
    int4*   Ta_s = (int4*)(tb + 2 * 147456 + 589824);

    // ---- 0) detect + ingest ----
    detect_k<<<dim3(1), blk, 0, stream>>>((const unsigned short*)d_in[0], flag);
    long woff[22];
    {
        long acc = 0;
        for (int i = 2; i < 22; i++) { woff[i] = acc; acc += (in_sizes[i] + 7) & ~7L; }
    }
    IArgs ia;
    long tot = 0;
    auto seg = [&](int s, const void* src, float* dst, long n) {
        ia.src[s] = src; ia.dst[s] = dst; ia.start[s] = tot; tot += n;
    };
    seg(0, d_in[0], xt32, (long)B * C * Nt);
    seg(1, d_in[0], at,   (long)B * C * Nt);
    seg(2, d_in[1], xs32, (long)B * C * Ns);
    seg(3, d_in[1], asr,  (long)B * C * Ns);
    for (int i = 2; i < 22; i++) seg(2 + i, d_in[i], Wf + woff[i], in_sizes[i]);
    ia.start[NSEG] = tot;
    ingest_all_k<<<dim3((unsigned)((tot + 255) / 256)), blk, 0, stream>>>(ia, flag);

    const float *tq_w = Wf + woff[2],  *tq_b = Wf + woff[3];
    const float *tk_w = Wf + woff[4],  *tk_b = Wf + woff[5];
    const float *tv_w = Wf + woff[6],  *tv_b = Wf + woff[7];
    const float *sq_w = Wf + woff[8],  *sq_b = Wf + woff[9];
    const float *sk_w = Wf + woff[10], *sk_b = Wf + woff[11];
    const float *sv_w = Wf + woff[12], *sv_b = Wf + woff[13];
    const float *t_off_w = Wf + woff[14], *t_off_b = Wf + woff[15];
    const float *t_dcn_w = Wf + woff[16], *t_dcn_b = Wf + woff[17];
    const float *s_off_w = Wf + woff[18], *s_off_b = Wf + woff[19];
    const float *s_dcn_w = Wf + woff[20], *s_dcn_b = Wf + woff[21];

    // ---- 1) transposes + prefills ----
    tr_k<<<dim3(Nt / 32, 8, B), dim3(32, 8), 0, stream>>>(xt32, xtT, Nt);
    tr_k<<<dim3(Ns / 32, 8, B), dim3(32, 8), 0, stream>>>(xs32, xsT, Ns);
    fill_k<<<dim3((2 * B * C * C) / 256), blk, 0, stream>>>(gram_t, nullptr, 1, 1, 2L * B * C * C);
    fill_k<<<dim3((B * 27 * Nt + 255) / 256), blk, 0, stream>>>(oo_t, t_off_b, 27L * Nt, Nt, (long)B * 27 * Nt);
    fill_k<<<dim3((B * 27 * Ns + 255) / 256), blk, 0, stream>>>(oo_s, s_off_b, 27L * Ns, Ns, (long)B * 27 * Ns);

    // ---- 2) q,k,v projections (B = x^T, BMODE1, PREC2) ----
    mgemm<false, 1, false, true, 2, 1><<<dim3(Nt / 64, 1, B), blk, 0, stream>>>(
        tq_w, 256, 1, 0, xtT, 256, sXt, q_t, Nt, (long)32 * Nt, tq_b, 32, Nt, 256, 0, 0);
    mgemm<false, 1, false, true, 2, 1><<<dim3(Nt / 64, 1, B), blk, 0, stream>>>(
        tk_w, 256, 1, 0, xtT, 256, sXt, k_t, Nt, (long)32 * Nt, tk_b, 32, Nt, 256, 0, 0);
    mgemm<false, 1, false, true, 2, 1><<<dim3(Nt / 64, 4, B), blk, 0, stream>>>(
        tv_w, 256, 1, 0, xtT, 256, sXt, v_t, Nt, sXt, tv_b, 256, Nt, 256, 0, 0);
    mgemm<false, 1, false, true, 2, 1><<<dim3(Ns / 64, 1, B), blk, 0, stream>>>(
        sq_w, 256, 1, 0, xsT, 256, sXs, q_s, Ns, (long)32 * Ns, sq_b, 32, Ns, 256, 0, 0);
    mgemm<false, 1, false, true, 2, 1><<<dim3(Ns / 64, 1, B), blk, 0, stream>>>(
        sk_w, 256, 1, 0, xsT, 256, sXs, k_s, Ns, (long)32 * Ns, sk_b, 32, Ns, 256, 0, 0);
    mgemm<false, 1, false, true, 2, 1><<<dim3(Ns / 64, 4, B), blk, 0, stream>>>(
        sv_w, 256, 1, 0, xsT, 256, sXs, v_s, Ns, sXs, sv_b, 256, Ns, 256, 0, 0);

    // ---- 3) gram matrices (BMODE1, K-split 4) ----
    mgemm<false, 1, false, false, 1, 4><<<dim3(4, 16, B), blk, 0, stream>>>(
        xt32, Nt, 1, sXt, xt32, Nt, sXt, gram_t, 256, (long)C * C, nullptr, 256, 256, Nt, 0, 0);
    mgemm<false, 1, false, false, 1, 4><<<dim3(4, 16, B), blk, 0, stream>>>(
        xs32, Ns, 1, sXs, xs32, Ns, sXs, gram_s, 256, (long)C * C, nullptr, 256, 256, Ns, 0, 0);

    // ---- 4) M ----
    gram_sm_k<<<dim3(B, 4), dim3(64), 0, stream>>>(gram_t, gram_s, Mc);

    // ---- 5) channel attention (B = x^T, BMODE1) ----
    mgemm<false, 1, true, false, 2, 2><<<dim3(Nt / 64, 8, B), blk, 0, stream>>>(
        Mc, 256, 1, (long)C * C, xtT, 256, sXt, at, Nt, sXt, nullptr, 256, Nt, 256, 0, 0);
    mgemm<false, 1, true, false, 2, 1><<<dim3(Ns / 64, 4, B), blk, 0, stream>>>(
        Mc, 256, 1, (long)C * C, xsT, 256, sXs, asr, Ns, sXs, nullptr, 256, Ns, 256, 0, 0);

    // ---- 6) template spatial attention (transposed logits) ----
    mgemm<true, 0, false, false, 2, 1><<<dim3(4, 4, B), blk, 0, stream>>>(
        k_t, Nt, 1, (long)32 * Nt, q_t, Nt, (long)32 * Nt, att_t, Nt, (long)Nt * Nt,
        nullptr, Nt, Nt, 32, 0, 0);
    softmax_b_k<<<dim3((Nt * Nt) / 256), blk, 0, stream>>>(att_t, (long)Nt * Nt);
    mgemm<false, 1, true, false, 2, 2><<<dim3(Nt / 64, 8, B), blk, 0, stream>>>(
        v_t, Nt, 1, sXt, att_t, Nt, (long)Nt * Nt, at, Nt, sXt, nullptr, 256, Nt, Nt, 0, 0);

    // ---- 7) search spatial attention, 4 m-slabs (transposed logits) ----
    for (int m0s = 0; m0s < Ns; m0s += 256) {
        mgemm<true, 0, false, false, 2, 1><<<dim3(Ns / 64, 4, B), blk, 0, stream>>>(
            k_s + m0s, Ns, 1, (long)32 * Ns, q_s, Ns, (long)32 * Ns,
            att_slab, Ns, (long)256 * Ns, nullptr, 256, Ns, 32, 0, 0);
        softmax_b_k<<<dim3((256 * Ns) / 256), blk, 0, stream>>>(att_slab, (long)256 * Ns);
        mgemm<false, 1, true, false, 2, 4><<<dim3(4, 16, B), blk, 0, stream>>>(
            v_s, Ns, 1, sXs, att_slab, Ns, (long)256 * Ns,
            asr + m0s, Ns, sXs, nullptr, 256, 256, Ns, 0, 0);
    }

    // ---- 8) offset convs (im2col, K-split 4, bias prefilled) ----
    mgemm<false, 3, false, false, 2, 4><<<dim3(Nt / 64, 4, B), blk, 0, stream>>>(
        t_off_w, 2304, 1, 0, at, Nt, sXt, oo_t, Nt, (long)27 * Nt,
        nullptr, 27, Nt, 2304, 16, 4);
    mgemm<false, 3, false, false, 2, 4><<<dim3(Ns / 64, 4, B), blk, 0, stream>>>(
        s_off_w, 2304, 1, 0, asr, Ns, sXs, oo_s, Ns, (long)27 * Ns,
        nullptr, 27, Ns, 2304, 32, 5);

    // ---- 9) DCN prep (v_s region dead; att_t/att_slab dead after step 7) ----
    wre4_k<<<dim3((2304 * 256) / 256), blk, 0, stream>>>(t_dcn_w, Wi_t);
    wre4_k<<<dim3((2304 * 256) / 256), blk, 0, stream>>>(s_dcn_w, Wi_s);
    dcnw_k<<<dim3((B * 9 * Nt) / 256), blk, 0, stream>>>(oo_t, Tw_t, Ta_t, Nt, 16, 16);
    dcnw_k<<<dim3((B * 9 * Ns) / 256), blk, 0, stream>>>(oo_s, Tw_s, Ta_s, Ns, 32, 32);
    // transpose attention outputs to [n][c] for channel-contiguous sampling
    tr_k<<<dim3(Nt / 32, 8, B), dim3(32, 8), 0, stream>>>(at, atT, Nt);
    tr_k<<<dim3(Ns / 32, 8, B), dim3(32, 8), 0, stream>>>(asr, asrT, Ns);

    // ---- 10) deformable convs: sample both, then ONE fused 1280-block GEMM ----
    // (samp_t overwrites the dead at/asr region with Si_t — after both tr_k's.)
    samp_k<<<dim3(Nt / 64, 9, B), blk, 0, stream>>>(Tw_t, Ta_t, atT, Si_t, Nt, 256);
    samp_k<<<dim3(Ns / 64, 9, B), blk, 0, stream>>>(Tw_s, Ta_s, asrT, Si, Ns, 1024);
    dcn9_k<<<dim3(1280), blk, 0, stream>>>(Wi_s, Si, Wi_t, Si_t,
                                           s_dcn_b, t_dcn_b, out_s_f32, out_t_f32);

    // ---- 11) emit output ----
    long nt = (long)B * C * Nt;
    long ntot = nt + (long)B * C * Ns;
    cast_out_k<<<dim3((unsigned)((ntot + 255) / 256)), blk, 0, stream>>>(
        out_t_f32, out_s_f32, d_out, nt, ntot, flag);
}

// Round 13
// 810.124 us; speedup vs baseline: 1.0158x; 1.0158x over previous
//
#include <hip/hip_runtime.h>
#include <hip/hip_bf16.h>

typedef __hip_bfloat16 bf16;
typedef __attribute__((ext_vector_type(8))) short short8;
typedef __attribute__((ext_vector_type(4))) short short4v;
typedef __attribute__((ext_vector_type(4))) float f32x4;

__device__ __forceinline__ short f2b(float v)
{
    union { bf16 b; short s; } u;
    u.b = __float2bfloat16(v);
    return u.s;
}
__device__ __forceinline__ float b2f(short s)
{
    union { short s; bf16 b; } u;
    u.s = s;
    return __bfloat162float(u.b);
}
__device__ __forceinline__ void splt(float v, short& hi, short& lo)
{
    hi = f2b(v);
    lo = f2b(v - b2f(hi));
}
__device__ __forceinline__ int bsw(int row, int g)
{
    return row * 40 + (((g + (row >> 3)) & 3) << 3);
}

// ---------------------------------------------------------------------------
// Dtype detector (validated r2): flag=1 -> fp32 storage, 0 -> bf16.
// ---------------------------------------------------------------------------
__global__ void detect_k(const unsigned short* __restrict__ p, int* __restrict__ flag)
{
    __shared__ int cnt;
    if (threadIdx.x == 0) cnt = 0;
    __syncthreads();
    int bad = 0;
    for (int i = threadIdx.x; i < 4096; i += 256) {
        unsigned short u = p[2 * i];
        int e = (u >> 7) & 0xFF;
        if (e != 0 && (e < 100 || e > 140)) bad++;
    }
    atomicAdd(&cnt, bad);
    __syncthreads();
    if (threadIdx.x == 0) *flag = (cnt > 1024) ? 1 : 0;
}

// ---------------------------------------------------------------------------
// Fused ingest (validated r5)
// ---------------------------------------------------------------------------
#define NSEG 24
struct IArgs {
    const void* src[NSEG];
    float* dst[NSEG];
    long start[NSEG + 1];
};

__global__ void ingest_all_k(IArgs a, const int* __restrict__ flag)
{
    long i = (long)blockIdx.x * 256 + threadIdx.x;
    if (i >= a.start[NSEG]) return;
    int s = 0;
#pragma unroll
    for (int j = 1; j < NSEG; j++) s += (i >= a.start[j]) ? 1 : 0;
    long idx = i - a.start[s];
    float v;
    if (*flag) v = ((const float*)a.src[s])[idx];
    else       v = __bfloat162float(((const bf16*)a.src[s])[idx]);
    a.dst[s][idx] = v;
}

// C[b][m][n] = bias[m] (or 0).  total = B*MN.
__global__ void fill_k(float* __restrict__ C, const float* __restrict__ bias,
                       long MN, int Nn, long total)
{
    long i = (long)blockIdx.x * 256 + threadIdx.x;
    if (i >= total) return;
    float v = 0.f;
    if (bias) {
        long r = i % MN;
        v = bias[(int)(r / Nn)];
    }
    C[i] = v;
}

// Tiled transpose: X[b][c][n] -> XT[b][n][c].  C=256. grid (N/32, 8, B), blk (32,8)
__global__ void tr_k(const float* __restrict__ X, float* __restrict__ XT, int N)
{
    __shared__ float t[32][33];
    int b = blockIdx.z, n0 = blockIdx.x * 32, c0 = blockIdx.y * 32;
    const float* Xb = X + (long)b * 256 * N;
    float* Tb = XT + (long)b * 256 * N;
    int tx = threadIdx.x, ty = threadIdx.y;
#pragma unroll
    for (int i = 0; i < 4; i++)
        t[ty + 8 * i][tx] = Xb[(long)(c0 + ty + 8 * i) * N + n0 + tx];
    __syncthreads();
#pragma unroll
    for (int i = 0; i < 4; i++)
        Tb[(long)(n0 + ty + 8 * i) * 256 + c0 + tx] = t[tx][ty + 8 * i];
}

// ---------------------------------------------------------------------------
// MFMA bf16 GEMM (validated r8/r9) — non-DCN ops.
// r12 post-mortem: PREC1 on attn/offset paths FAILED (absmax 1.19) — the
// offset conv output is position-sensitive: offset err eps -> sampled-value
// err ~ eps * |spatial gradient| (~20x gain).  Everything feeding the
// offset conv (channel attn, PV, offset conv itself) must stay PREC2.
// ---------------------------------------------------------------------------
template <bool TRA, int BMODE, bool ACCUM, bool BIAS, int PREC, int KSPLIT>
__launch_bounds__(256)
__global__ void mgemm(const float* __restrict__ A, int lda, int ksA, long sA,
                      const void* __restrict__ Bsrc, int ldb, long sB,
                      float* __restrict__ C, int ldc, long sC,
                      const float* __restrict__ bias,
                      int M, int N, int K, int H, int wsh)
{
    __shared__ short As[PREC * 2560];
    __shared__ short Bs[PREC * 2560];

    const int bz = blockIdx.z;
    const float* Ab = A + (long)bz * sA;
    float* Cb = C + (long)bz * sC;
    const int mt = blockIdx.y / KSPLIT, ch = blockIdx.y % KSPLIT;
    const int m0 = mt * 64, n0 = blockIdx.x * 64;
    const int kchunk = K / KSPLIT;
    const int kbeg = ch * kchunk, kend = kbeg + kchunk;
    const int tid = threadIdx.x;

    f32x4 acc[2][2];
#pragma unroll
    for (int i = 0; i < 2; i++)
#pragma unroll
        for (int j = 0; j < 2; j++) acc[i][j] = (f32x4){0.f, 0.f, 0.f, 0.f};

    const int lane = tid & 63, wv = tid >> 6;
    const int moff = (wv & 1) * 32, noff = (wv >> 1) * 32;
    const int lr = lane & 15, lq = lane >> 4;
    const int mm = tid >> 2, kk0 = (tid & 3) * 8;
    const int nn = tid & 63, kg = tid >> 6;

    for (int k0 = kbeg; k0 < kend; k0 += 32) {
        // ---- stage A ----
        {
            float vv[8];
            if (m0 + mm < M) {
                if (!TRA) {
                    if (ksA == 1) {
                        const float4* s4 = (const float4*)(Ab + (long)(m0 + mm) * lda + k0 + kk0);
                        float4 v0 = s4[0], v1 = s4[1];
                        vv[0] = v0.x; vv[1] = v0.y; vv[2] = v0.z; vv[3] = v0.w;
                        vv[4] = v1.x; vv[5] = v1.y; vv[6] = v1.z; vv[7] = v1.w;
                    } else {
                        const float* s = Ab + (long)(m0 + mm) * lda + (long)(k0 + kk0) * ksA;
#pragma unroll
                        for (int j = 0; j < 8; j++) vv[j] = s[(long)j * ksA];
                    }
                } else {
#pragma unroll
                    for (int j = 0; j < 8; j++)
                        vv[j] = Ab[(long)(k0 + kk0 + j) * lda + m0 + mm];
                }
            } else {
#pragma unroll
                for (int j = 0; j < 8; j++) vv[j] = 0.f;
            }
            short8 hi, lo;
#pragma unroll
            for (int j = 0; j < 8; j++) { short h, l; splt(vv[j], h, l); hi[j] = h; lo[j] = l; }
            *(short8*)&As[mm * 40 + kk0] = hi;
            if (PREC == 2) *(short8*)&As[2560 + mm * 40 + kk0] = lo;
        }

        // ---- stage B ----
        if (BMODE == 1) {
            const float4* s4 = (const float4*)((const float*)Bsrc + (long)bz * sB +
                                               (long)(n0 + mm) * ldb + k0 + kk0);
            float4 v0 = s4[0], v1 = s4[1];
            float vv[8] = {v0.x, v0.y, v0.z, v0.w, v1.x, v1.y, v1.z, v1.w};
            short8 hi, lo;
#pragma unroll
            for (int j = 0; j < 8; j++) { short h, l; splt(vv[j], h, l); hi[j] = h; lo[j] = l; }
            int o = bsw(mm, tid & 3);
            *(short8*)&Bs[o] = hi;
            if (PREC == 2) *(short8*)&Bs[2560 + o] = lo;
        } else {
            float vv[8];
            if (BMODE == 0) {
#pragma unroll
                for (int j = 0; j < 8; j++)
                    vv[j] = ((const float*)Bsrc)[(long)bz * sB + (long)(k0 + kg * 8 + j) * ldb + n0 + nn];
            } else {  // BMODE 3: im2col
                int W = 1 << wsh;
                int n = n0 + nn;
                int hbase = n >> wsh, wbase = n & (W - 1);
#pragma unroll
                for (int j = 0; j < 8; j++) {
                    int kc = k0 + kg * 8 + j;
                    int c = kc / 9, tap = kc - 9 * c;
                    int h = hbase + tap / 3 - 1, w = wbase + tap % 3 - 1;
                    vv[j] = (h >= 0 && h < H && w >= 0 && w < W)
                          ? ((const float*)Bsrc)[(long)bz * sB + (long)c * ldb + (h << wsh) + w]
                          : 0.f;
                }
            }
            short8 hi, lo;
#pragma unroll
            for (int j = 0; j < 8; j++) { short h, l; splt(vv[j], h, l); hi[j] = h; lo[j] = l; }
            int o = bsw(nn, kg);
            *(short8*)&Bs[o] = hi;
            if (PREC == 2) *(short8*)&Bs[2560 + o] = lo;
        }
        __syncthreads();

        // ---- compute ----
        int rb0 = noff + lr, rb1 = noff + 16 + lr;
        short8 a0h = *(short8*)&As[(moff + lr) * 40 + lq * 8];
        short8 a1h = *(short8*)&As[(moff + 16 + lr) * 40 + lq * 8];
        short8 b0h = *(short8*)&Bs[bsw(rb0, lq)];
        short8 b1h = *(short8*)&Bs[bsw(rb1, lq)];
        acc[0][0] = __builtin_amdgcn_mfma_f32_16x16x32_bf16(a0h, b0h, acc[0][0], 0, 0, 0);
        acc[0][1] = __builtin_amdgcn_mfma_f32_16x16x32_bf16(a0h, b1h, acc[0][1], 0, 0, 0);
        acc[1][0] = __builtin_amdgcn_mfma_f32_16x16x32_bf16(a1h, b0h, acc[1][0], 0, 0, 0);
        acc[1][1] = __builtin_amdgcn_mfma_f32_16x16x32_bf16(a1h, b1h, acc[1][1], 0, 0, 0);
        if (PREC == 2) {
            short8 a0l = *(short8*)&As[2560 + (moff + lr) * 40 + lq * 8];
            short8 a1l = *(short8*)&As[2560 + (moff + 16 + lr) * 40 + lq * 8];
            short8 b0l = *(short8*)&Bs[2560 + bsw(rb0, lq)];
            short8 b1l = *(short8*)&Bs[2560 + bsw(rb1, lq)];
            acc[0][0] = __builtin_amdgcn_mfma_f32_16x16x32_bf16(a0h, b0l, acc[0][0], 0, 0, 0);
            acc[0][1] = __builtin_amdgcn_mfma_f32_16x16x32_bf16(a0h, b1l, acc[0][1], 0, 0, 0);
            acc[1][0] = __builtin_amdgcn_mfma_f32_16x16x32_bf16(a1h, b0l, acc[1][0], 0, 0, 0);
            acc[1][1] = __builtin_amdgcn_mfma_f32_16x16x32_bf16(a1h, b1l, acc[1][1], 0, 0, 0);
            acc[0][0] = __builtin_amdgcn_mfma_f32_16x16x32_bf16(a0l, b0h, acc[0][0], 0, 0, 0);
            acc[0][1] = __builtin_amdgcn_mfma_f32_16x16x32_bf16(a0l, b1h, acc[0][1], 0, 0, 0);
            acc[1][0] = __builtin_amdgcn_mfma_f32_16x16x32_bf16(a1l, b0h, acc[1][0], 0, 0, 0);
            acc[1][1] = __builtin_amdgcn_mfma_f32_16x16x32_bf16(a1l, b1h, acc[1][1], 0, 0, 0);
        }
        __syncthreads();
    }

    // ---- epilogue ----
#pragma unroll
    for (int mi = 0; mi < 2; mi++)
#pragma unroll
        for (int ni = 0; ni < 2; ni++) {
            int col = n0 + noff + ni * 16 + lr;
#pragma unroll
            for (int r = 0; r < 4; r++) {
                int row = m0 + moff + mi * 16 + lq * 4 + r;
                if (row < M) {
                    long o = (long)row * ldc + col;
                    float v = acc[mi][ni][r];
                    if (KSPLIT > 1) {
                        atomicAdd(&Cb[o], v);
                    } else {
                        if (BIAS) v += bias[row];
                        if (ACCUM) v += Cb[o];
                        Cb[o] = v;
                    }
                }
            }
        }
}

// ---------------------------------------------------------------------------
// DCN bilinear corner tables
// ---------------------------------------------------------------------------
__global__ void dcnw_k(const float* __restrict__ OO, float4* __restrict__ Tw,
                       int4* __restrict__ Ta, int N, int H, int W)
{
    long idx = (long)blockIdx.x * 256 + threadIdx.x;
    if (idx >= (long)16 * 9 * N) return;
    int b = (int)(idx / (9 * N));
    int r = (int)(idx % (9 * N));
    int tap = r / N, p = r % N;
    int h = p / W, w = p % W;
    const float* oob = OO + (long)b * 27 * N;
    float oy = oob[(2 * tap) * N + p];
    float ox = oob[(2 * tap + 1) * N + p];
    float mz = oob[(18 + tap) * N + p];
    float mask = 1.f / (1.f + expf(-mz));
    float y = (float)(h - 1 + tap / 3) + oy;
    float x = (float)(w - 1 + tap % 3) + ox;
    float y0 = floorf(y), x0 = floorf(x);
    float wy = y - y0, wx = x - x0;
    float ys[2] = {y0, y0 + 1.f};
    float xs[2] = {x0, x0 + 1.f};
    float wys[2] = {1.f - wy, wy};
    float wxs[2] = {1.f - wx, wx};
    float wv[4]; int av[4];
#pragma unroll
    for (int iy = 0; iy < 2; iy++)
#pragma unroll
        for (int ix = 0; ix < 2; ix++) {
            float yy = ys[iy], xx = xs[ix];
            bool valid = (yy >= 0.f) && (yy <= (float)(H - 1)) &&
                         (xx >= 0.f) && (xx <= (float)(W - 1));
            wv[iy * 2 + ix] = valid ? wys[iy] * wxs[ix] * mask : 0.f;
            int yc = (int)fminf(fmaxf(yy, 0.f), (float)(H - 1));
            int xc = (int)fminf(fmaxf(xx, 0.f), (float)(W - 1));
            av[iy * 2 + ix] = yc * W + xc;
        }
    Tw[idx] = (float4){wv[0], wv[1], wv[2], wv[3]};
    Ta[idx] = (int4){av[0], av[1], av[2], av[3]};
}

// ---------------------------------------------------------------------------
// DCN weight prepack (r19, validated): SINGLE-PLANE bf16,
// Wh[o][tap*256 + c], row stride 2304 shorts.
// ---------------------------------------------------------------------------
__global__ void wre4_k(const float* __restrict__ W, short* __restrict__ Wh)
{
    long idx = (long)blockIdx.x * 256 + threadIdx.x;
    if (idx >= 2304L * 256) return;
    int o = (int)(idx / 2304);
    int k = (int)(idx % 2304);
    int tap = k >> 8, c = k & 255;
    Wh[(long)o * 2304 + tap * 256 + c] = f2b(W[((long)o * 256 + c) * 9 + tap]);
}

// ---------------------------------------------------------------------------
// samp_k (r18, validated): WAVE-COALESCED gather.  4-lane group owns one n;
// lane cc2 reads float4 index q*4+cc2 of each corner row -> one contiguous
// 64B line per group per instruction.  Grid: (N/64, 9, B), blk 256.
// ---------------------------------------------------------------------------
__global__ void samp_k(const float4* __restrict__ Tw, const int4* __restrict__ Ta,
                       const float* __restrict__ XT, short* __restrict__ Si,
                       int N, int NRND)
{
    int tid = threadIdx.x;
    int g = tid >> 2, cc2 = tid & 3;
    int tap = blockIdx.y, b = blockIdx.z;
    int n = blockIdx.x * 64 + g;
    long ti = ((long)(b * 9 + tap)) * N + n;
    float4 w4 = Tw[ti];
    int4 a4 = Ta[ti];
    const float* Xb = XT + (long)b * 256 * N;
    const float4* r0 = (const float4*)(Xb + (long)a4.x * 256);
    const float4* r1 = (const float4*)(Xb + (long)a4.y * 256);
    const float4* r2 = (const float4*)(Xb + (long)a4.z * 256);
    const float4* r3 = (const float4*)(Xb + (long)a4.w * 256);
    long so = ((long)b * NRND + n) * 2304 + tap * 256;
    short4v out[16];
#pragma unroll
    for (int q = 0; q < 16; q++) {
        int i = q * 4 + cc2;
        float4 p = r0[i], qv = r1[i], s = r2[i], t = r3[i];
        out[q][0] = f2b(w4.x * p.x + w4.y * qv.x + w4.z * s.x + w4.w * t.x);
        out[q][1] = f2b(w4.x * p.y + w4.y * qv.y + w4.z * s.y + w4.w * t.y);
        out[q][2] = f2b(w4.x * p.z + w4.y * qv.z + w4.z * s.z + w4.w * t.z);
        out[q][3] = f2b(w4.x * p.w + w4.y * qv.w + w4.z * s.w + w4.w * t.w);
    }
#pragma unroll
    for (int q = 0; q < 16; q++)
        *(short4v*)&Si[so + q * 16 + cc2 * 4] = out[q];
}

// ---------------------------------------------------------------------------
// Deformable conv v11 (dcn9, r22): fused template+search 1280-block dispatch,
// __launch_bounds__(256,4), 32-bit offsets, unroll 2 (restores the cross-
// iteration load/MFMA overlap r11's unroll-1 lost; VGPR 48 had headroom).
// ---------------------------------------------------------------------------
__launch_bounds__(256, 4)
__global__ void dcn9_k(const short* __restrict__ Wh_s, const short* __restrict__ Si_s,
                       const short* __restrict__ Wh_t, const short* __restrict__ Si_t,
                       const float* __restrict__ bias_s, const float* __restrict__ bias_t,
                       float* __restrict__ Cs, float* __restrict__ Ct)
{
    __shared__ float red[8192];               // 2 slots x 64 fidx x 64 lanes

    int bid = blockIdx.x;
    const short* Wh; const short* Si; const float* bias; float* Cb;
    int N, mt, nt;
    if (bid < 1024) {                         // search: 16bz x 4mt x 16nt
        int bz = bid >> 6, t = bid & 63;
        mt = t >> 4; nt = t & 15;
        Wh = Wh_s; Si = Si_s + (long)bz * 1024 * 2304;
        bias = bias_s; Cb = Cs + (long)bz * 256 * 1024; N = 1024;
    } else {                                  // template: 16bz x 4mt x 4nt
        int r = bid - 1024;
        int bz = r >> 4, t = r & 15;
        mt = t >> 2; nt = t & 3;
        Wh = Wh_t; Si = Si_t + (long)bz * 256 * 2304;
        bias = bias_t; Cb = Ct + (long)bz * 256 * 256; N = 256;
    }
    const int m0 = mt * 64, n0 = nt * 64;

    const int tid = threadIdx.x;
    const int lane = tid & 63, wv = tid >> 6;
    const int lr = lane & 15, lq = lane >> 4;

    int aoff[4], boff[4];
#pragma unroll
    for (int mi = 0; mi < 4; mi++)
        aoff[mi] = (m0 + mi * 16 + lr) * 2304 + lq * 8;
#pragma unroll
    for (int ni = 0; ni < 4; ni++)
        boff[ni] = (n0 + ni * 16 + lr) * 2304 + lq * 8;

    f32x4 acc[4][4];
#pragma unroll
    for (int i = 0; i < 4; i++)
#pragma unroll
        for (int j = 0; j < 4; j++) acc[i][j] = (f32x4){0.f, 0.f, 0.f, 0.f};

    // ---- main loop: this wave's 18-kt K-chunk ----
    const int kbeg = wv * 18;
#pragma unroll 2
    for (int kt = kbeg; kt < kbeg + 18; kt++) {
        int koff = (kt >> 3) * 256 + (kt & 7) * 32;
        short8 ah[4], bh[4];
#pragma unroll
        for (int ni = 0; ni < 4; ni++)
            bh[ni] = *(const short8*)&Si[boff[ni] + koff];
#pragma unroll
        for (int mi = 0; mi < 4; mi++)
            ah[mi] = *(const short8*)&Wh[aoff[mi] + koff];
#pragma unroll
        for (int mi = 0; mi < 4; mi++)
#pragma unroll
            for (int ni = 0; ni < 4; ni++)
                acc[mi][ni] = __builtin_amdgcn_mfma_f32_16x16x32_bf16(ah[mi], bh[ni], acc[mi][ni], 0, 0, 0);
    }

    // ---- LDS tree reduction (lane-stride-4B layout: conflict-free b32) ----
    if (wv == 1 || wv == 3) {
        float* rp = &red[(wv == 1 ? 0 : 4096) + lane];
#pragma unroll
        for (int mi = 0; mi < 4; mi++)
#pragma unroll
            for (int ni = 0; ni < 4; ni++)
#pragma unroll
                for (int r2 = 0; r2 < 4; r2++)
                    rp[(mi * 16 + ni * 4 + r2) << 6] = acc[mi][ni][r2];
    }
    __syncthreads();
    if (wv == 0) {
        const float* rp = &red[lane];
#pragma unroll
        for (int mi = 0; mi < 4; mi++)
#pragma unroll
            for (int ni = 0; ni < 4; ni++)
#pragma unroll
                for (int r2 = 0; r2 < 4; r2++)
                    acc[mi][ni][r2] += rp[(mi * 16 + ni * 4 + r2) << 6];
    } else if (wv == 2) {
        float* rp = &red[4096 + lane];
#pragma unroll
        for (int mi = 0; mi < 4; mi++)
#pragma unroll
            for (int ni = 0; ni < 4; ni++)
#pragma unroll
                for (int r2 = 0; r2 < 4; r2++) {
                    int o = (mi * 16 + ni * 4 + r2) << 6;
                    float v = acc[mi][ni][r2] + rp[o];
                    rp[o] = v;
                }
    }
    __syncthreads();
    if (wv == 0) {
        const float* rp = &red[4096 + lane];
#pragma unroll
        for (int mi = 0; mi < 4; mi++)
#pragma unroll
            for (int ni = 0; ni < 4; ni++) {
                int col = n0 + ni * 16 + lr;
#pragma unroll
                for (int r2 = 0; r2 < 4; r2++) {
                    int row = m0 + mi * 16 + lq * 4 + r2;
                    float v = acc[mi][ni][r2] + rp[(mi * 16 + ni * 4 + r2) << 6];
                    Cb[(long)row * N + col] = v + bias[row];
                }
            }
    }
}

// Softmax over batch axis (16)
__global__ void softmax_b_k(float* __restrict__ att, long NN)
{
    long idx = (long)blockIdx.x * 256 + threadIdx.x;
    if (idx >= NN) return;
    float r[16];
    float mx = -1e30f;
#pragma unroll
    for (int b = 0; b < 16; b++) {
        r[b] = att[(long)b * NN + idx];
        mx = fmaxf(mx, r[b]);
    }
    float s = 0.f;
#pragma unroll
    for (int b = 0; b < 16; b++) { r[b] = expf(r[b] - mx); s += r[b]; }
    float inv = 1.f / s;
#pragma unroll
    for (int b = 0; b < 16; b++) att[(long)b * NN + idx] = r[b] * inv;
}

// M[b][c][d] = softmax_c(gram_t) + softmax_c(gram_s)
__global__ void gram_sm_k(const float* __restrict__ gt, const float* __restrict__ gs,
                          float* __restrict__ Mo)
{
    int b = blockIdx.x;
    int d = blockIdx.y * 64 + threadIdx.x;
    const float* gtb = gt + (long)b * 65536;
    const float* gsb = gs + (long)b * 65536;
    float* mb = Mo + (long)b * 65536;
    float mt = -1e30f, ms = -1e30f;
    for (int c = 0; c < 256; c++) {
        mt = fmaxf(mt, gtb[c * 256 + d]);
        ms = fmaxf(ms, gsb[c * 256 + d]);
    }
    float st = 0.f, ss = 0.f;
    for (int c = 0; c < 256; c++) {
        st += expf(gtb[c * 256 + d] - mt);
        ss += expf(gsb[c * 256 + d] - ms);
    }
    float it = 1.f / st, is = 1.f / ss;
    for (int c = 0; c < 256; c++)
        mb[c * 256 + d] = expf(gtb[c * 256 + d] - mt) * it +
                          expf(gsb[c * 256 + d] - ms) * is;
}

__global__ void cast_out_k(const float* __restrict__ t, const float* __restrict__ s,
                           void* __restrict__ out, long nt, long ntot,
                           const int* __restrict__ flag)
{
    long idx = (long)blockIdx.x * 256 + threadIdx.x;
    if (idx >= ntot) return;
    float v = (idx < nt) ? t[idx] : s[idx - nt];
    if (*flag) ((float*)out)[idx] = v;
    else       ((bf16*)out)[idx] = __float2bfloat16(v);
}

// ---------------------------------------------------------------------------
extern "C" void kernel_launch(void* const* d_in, const int* in_sizes, int n_in,
                              void* d_out, int out_size, void* d_ws, size_t ws_size,
                              hipStream_t stream)
{
    const int B = 16, C = 256;
    const int Nt = 256, Ns = 1024;
    const long sXt = (long)C * Nt, sXs = (long)C * Ns;
    dim3 blk(256);

    float* ws = (float*)d_ws;
    int* flag = (int*)d_ws;
    long off = 16;
    auto alloc = [&](long n) { float* p = ws + off; off += n; return p; };

    float* xt32     = alloc((long)B * C * Nt);
    float* xs32     = alloc((long)B * C * Ns);   // -> out_s_f32
    float* Wf       = alloc(1470464);
    float* q_t      = alloc((long)B * 32 * Nt);
    float* k_t      = alloc((long)B * 32 * Nt);
    float* v_t      = alloc((long)B * C * Nt);
    float* q_s      = alloc((long)B * 32 * Ns);
    float* k_s      = alloc((long)B * 32 * Ns);
    float* v_s      = alloc((long)B * C * Ns);   // -> DCN prep region
    float* gram_t   = alloc((long)B * C * C);    // -> out_t_f32
    float* gram_s   = alloc((long)B * C * C);
    float* Mc       = alloc((long)B * C * C);
    float* att_t    = alloc((long)B * Nt * Nt);  // xtT early / atT late
    float* att_slab = alloc((long)B * Ns * 256); // xsT early / asrT late
    float* at       = alloc((long)B * C * Nt);   // -> Si_t region late
    float* asr      = alloc((long)B * C * Ns);   // -> Si_t region late
    float* oo_t     = alloc((long)B * 27 * Nt);
    float* oo_s     = alloc((long)B * 27 * Ns);
    // Single-plane S: search NRND=1024 -> 16*1024*2304 shorts = 18.87M floats.
    float* Si_f     = alloc(18874368);
    short* Si = (short*)Si_f;

    float* out_t_f32 = gram_t;
    float* out_s_f32 = xs32;
    float* xtT       = att_t;
    float* xsT       = att_slab;
    float* atT       = att_t;     // reuse after attention phases complete
    float* asrT      = att_slab;  // reuse after attention phases complete
    // Template Si lives in the dead at+asr region (needs 4.72M floats < 5.24M).
    short* Si_t = (short*)at;
    short* Wi_t = (short*)v_s;                   // 589824 shorts each (hi-only)
    short* Wi_s = (short*)v_s + 589824;
    float* tb   = v_s + 1179648;
    float4* Tw_t = (float4*)tb;
    int4*   Ta_t = (int4*)(tb + 147456);
    float4* Tw_s = (float4*)(tb + 2 * 147456);
    int4*   Ta_s = (int4*)(tb + 2 * 147456 + 589824);

    // ---- 0) detect + ingest ----
    detect_k<<<dim3(1), blk, 0, stream>>>((const unsigned short*)d_in[0], flag);
    long woff[22];
    {
        long acc = 0;
        for (int i = 2; i < 22; i++) { woff[i] = acc; acc += (in_sizes[i] + 7) & ~7L; }
    }
    IArgs ia;
    long tot = 0;
    auto seg = [&](int s, const void* src, float* dst, long n) {
        ia.src[s] = src; ia.dst[s] = dst; ia.start[s] = tot; tot += n;
    };
    seg(0, d_in[0], xt32, (long)B * C * Nt);
    seg(1, d_in[0], at,   (long)B * C * Nt);
    seg(2, d_in[1], xs32, (long)B * C * Ns);
    seg(3, d_in[1], asr,  (long)B * C * Ns);
    for (int i = 2; i < 22; i++) seg(2 + i, d_in[i], Wf + woff[i], in_sizes[i]);
    ia.start[NSEG] = tot;
    ingest_all_k<<<dim3((unsigned)((tot + 255) / 256)), blk, 0, stream>>>(ia, flag);

    const float *tq_w = Wf + woff[2],  *tq_b = Wf + woff[3];
    const float *tk_w = Wf + woff[4],  *tk_b = Wf + woff[5];
    const float *tv_w = Wf + woff[6],  *tv_b = Wf + woff[7];
    const float *sq_w = Wf + woff[8],  *sq_b = Wf + woff[9];
    const float *sk_w = Wf + woff[10], *sk_b = Wf + woff[11];
    const float *sv_w = Wf + woff[12], *sv_b = Wf + woff[13];
    const float *t_off_w = Wf + woff[14], *t_off_b = Wf + woff[15];
    const float *t_dcn_w = Wf + woff[16], *t_dcn_b = Wf + woff[17];
    const float *s_off_w = Wf + woff[18], *s_off_b = Wf + woff[19];
    const float *s_dcn_w = Wf + woff[20], *s_dcn_b = Wf + woff[21];

    // ---- 1) transposes + prefills ----
    tr_k<<<dim3(Nt / 32, 8, B), dim3(32, 8), 0, stream>>>(xt32, xtT, Nt);
    tr_k<<<dim3(Ns / 32, 8, B), dim3(32, 8), 0, stream>>>(xs32, xsT, Ns);
    fill_k<<<dim3((2 * B * C * C) / 256), blk, 0, stream>>>(gram_t, nullptr, 1, 1, 2L * B * C * C);
    fill_k<<<dim3((B * 27 * Nt + 255) / 256), blk, 0, stream>>>(oo_t, t_off_b, 27L * Nt, Nt, (long)B * 27 * Nt);
    fill_k<<<dim3((B * 27 * Ns + 255) / 256), blk, 0, stream>>>(oo_s, s_off_b, 27L * Ns, Ns, (long)B * 27 * Ns);

    // ---- 2) q,k,v projections (B = x^T, BMODE1, PREC2) ----
    mgemm<false, 1, false, true, 2, 1><<<dim3(Nt / 64, 1, B), blk, 0, stream>>>(
        tq_w, 256, 1, 0, xtT, 256, sXt, q_t, Nt, (long)32 * Nt, tq_b, 32, Nt, 256, 0, 0);
    mgemm<false, 1, false, true, 2, 1><<<dim3(Nt / 64, 1, B), blk, 0, stream>>>(
        tk_w, 256, 1, 0, xtT, 256, sXt, k_t, Nt, (long)32 * Nt, tk_b, 32, Nt, 256, 0, 0);
    mgemm<false, 1, false, true, 2, 1><<<dim3(Nt / 64, 4, B), blk, 0, stream>>>(
        tv_w, 256, 1, 0, xtT, 256, sXt, v_t, Nt, sXt, tv_b, 256, Nt, 256, 0, 0);
    mgemm<false, 1, false, true, 2, 1><<<dim3(Ns / 64, 1, B), blk, 0, stream>>>(
        sq_w, 256, 1, 0, xsT, 256, sXs, q_s, Ns, (long)32 * Ns, sq_b, 32, Ns, 256, 0, 0);
    mgemm<false, 1, false, true, 2, 1><<<dim3(Ns / 64, 1, B), blk, 0, stream>>>(
        sk_w, 256, 1, 0, xsT, 256, sXs, k_s, Ns, (long)32 * Ns, sk_b, 32, Ns, 256, 0, 0);
    mgemm<false, 1, false, true, 2, 1><<<dim3(Ns / 64, 4, B), blk, 0, stream>>>(
        sv_w, 256, 1, 0, xsT, 256, sXs, v_s, Ns, sXs, sv_b, 256, Ns, 256, 0, 0);

    // ---- 3) gram matrices (BMODE1, K-split 4, PREC1 — validated since r0) ----
    mgemm<false, 1, false, false, 1, 4><<<dim3(4, 16, B), blk, 0, stream>>>(
        xt32, Nt, 1, sXt, xt32, Nt, sXt, gram_t, 256, (long)C * C, nullptr, 256, 256, Nt, 0, 0);
    mgemm<false, 1, false, false, 1, 4><<<dim3(4, 16, B), blk, 0, stream>>>(
        xs32, Ns, 1, sXs, xs32, Ns, sXs, gram_s, 256, (long)C * C, nullptr, 256, 256, Ns, 0, 0);

    // ---- 4) M ----
    gram_sm_k<<<dim3(B, 4), dim3(64), 0, stream>>>(gram_t, gram_s, Mc);

    // ---- 5) channel attention (B = x^T, BMODE1, PREC2 — r12 revert) ----
    mgemm<false, 1, true, false, 2, 2><<<dim3(Nt / 64, 8, B), blk, 0, stream>>>(
        Mc, 256, 1, (long)C * C, xtT, 256, sXt, at, Nt, sXt, nullptr, 256, Nt, 256, 0, 0);
    mgemm<false, 1, true, false, 2, 1><<<dim3(Ns / 64, 4, B), blk, 0, stream>>>(
        Mc, 256, 1, (long)C * C, xsT, 256, sXs, asr, Ns, sXs, nullptr, 256, Ns, 256, 0, 0);

    // ---- 6) template spatial attention (PREC2 — r12 revert) ----
    mgemm<true, 0, false, false, 2, 1><<<dim3(4, 4, B), blk, 0, stream>>>(
        k_t, Nt, 1, (long)32 * Nt, q_t, Nt, (long)32 * Nt, att_t, Nt, (long)Nt * Nt,
        nullptr, Nt, Nt, 32, 0, 0);
    softmax_b_k<<<dim3((Nt * Nt) / 256), blk, 0, stream>>>(att_t, (long)Nt * Nt);
    mgemm<false, 1, true, false, 2, 2><<<dim3(Nt / 64, 8, B), blk, 0, stream>>>(
        v_t, Nt, 1, sXt, att_t, Nt, (long)Nt * Nt, at, Nt, sXt, nullptr, 256, Nt, Nt, 0, 0);

    // ---- 7) search spatial attention, 4 m-slabs (PREC2 — r12 revert) ----
    for (int m0s = 0; m0s < Ns; m0s += 256) {
        mgemm<true, 0, false, false, 2, 1><<<dim3(Ns / 64, 4, B), blk, 0, stream>>>(
            k_s + m0s, Ns, 1, (long)32 * Ns, q_s, Ns, (long)32 * Ns,
            att_slab, Ns, (long)256 * Ns, nullptr, 256, Ns, 32, 0, 0);
        softmax_b_k<<<dim3((256 * Ns) / 256), blk, 0, stream>>>(att_slab, (long)256 * Ns);
        mgemm<false, 1, true, false, 2, 4><<<dim3(4, 16, B), blk, 0, stream>>>(
            v_s, Ns, 1, sXs, att_slab, Ns, (long)256 * Ns,
            asr + m0s, Ns, sXs, nullptr, 256, 256, Ns, 0, 0);
    }

    // ---- 8) offset convs (im2col, K-split 4, PREC2 — r12 revert) ----
    mgemm<false, 3, false, false, 2, 4><<<dim3(Nt / 64, 4, B), blk, 0, stream>>>(
        t_off_w, 2304, 1, 0, at, Nt, sXt, oo_t, Nt, (long)27 * Nt,
        nullptr, 27, Nt, 2304, 16, 4);
    mgemm<false, 3, false, false, 2, 4><<<dim3(Ns / 64, 4, B), blk, 0, stream>>>(
        s_off_w, 2304, 1, 0, asr, Ns, sXs, oo_s, Ns, (long)27 * Ns,
        nullptr, 27, Ns, 2304, 32, 5);

    // ---- 9) DCN prep (v_s region dead; att_t/att_slab dead after step 7) ----
    wre4_k<<<dim3((2304 * 256) / 256), blk, 0, stream>>>(t_dcn_w, Wi_t);
    wre4_k<<<dim3((2304 * 256) / 256), blk, 0, stream>>>(s_dcn_w, Wi_s);
    dcnw_k<<<dim3((B * 9 * Nt) / 256), blk, 0, stream>>>(oo_t, Tw_t, Ta_t, Nt, 16, 16);
    dcnw_k<<<dim3((B * 9 * Ns) / 256), blk, 0, stream>>>(oo_s, Tw_s, Ta_s, Ns, 32, 32);
    // transpose attention outputs to [n][c] for channel-contiguous sampling
    tr_k<<<dim3(Nt / 32, 8, B), dim3(32, 8), 0, stream>>>(at, atT, Nt);
    tr_k<<<dim3(Ns / 32, 8, B), dim3(32, 8), 0, stream>>>(asr, asrT, Ns);

    // ---- 10) deformable convs: sample both, then ONE fused 1280-block GEMM ----
    samp_k<<<dim3(Nt / 64, 9, B), blk, 0, stream>>>(Tw_t, Ta_t, atT, Si_t, Nt, 256);
    samp_k<<<dim3(Ns / 64, 9, B), blk, 0, stream>>>(Tw_s, Ta_s, asrT, Si, Ns, 1024);
    dcn9_k<<<dim3(1280), blk, 0, stream>>>(Wi_s, Si, Wi_t, Si_t,
                                           s_dcn_b, t_dcn_b, out_s_f32, out_t_f32);

    // ---- 11) emit output ----
    long nt = (long)B * C * Nt;
    long ntot = nt + (long)B * C * Ns;
    cast_out_k<<<dim3((unsigned)((ntot + 255) / 256)), blk, 0, stream>>>(
        out_t_f32, out_s_f32, d_out, nt, ntot, flag);
}

// Round 14
// 736.347 us; speedup vs baseline: 1.1176x; 1.1002x over previous
//
#include <hip/hip_runtime.h>
#include <hip/hip_bf16.h>

typedef __hip_bfloat16 bf16;
typedef __attribute__((ext_vector_type(8))) short short8;
typedef __attribute__((ext_vector_type(4))) short short4v;
typedef __attribute__((ext_vector_type(4))) float f32x4;

__device__ __forceinline__ short f2b(float v)
{
    union { bf16 b; short s; } u;
    u.b = __float2bfloat16(v);
    return u.s;
}
__device__ __forceinline__ float b2f(short s)
{
    union { short s; bf16 b; } u;
    u.s = s;
    return __bfloat162float(u.b);
}
__device__ __forceinline__ void splt(float v, short& hi, short& lo)
{
    hi = f2b(v);
    lo = f2b(v - b2f(hi));
}
__device__ __forceinline__ int bsw(int row, int g)
{
    return row * 40 + (((g + (row >> 3)) & 3) << 3);
}

// ---------------------------------------------------------------------------
// Dtype detector (validated r2): flag=1 -> fp32 storage, 0 -> bf16.
// ---------------------------------------------------------------------------
__global__ void detect_k(const unsigned short* __restrict__ p, int* __restrict__ flag)
{
    __shared__ int cnt;
    if (threadIdx.x == 0) cnt = 0;
    __syncthreads();
    int bad = 0;
    for (int i = threadIdx.x; i < 4096; i += 256) {
        unsigned short u = p[2 * i];
        int e = (u >> 7) & 0xFF;
        if (e != 0 && (e < 100 || e > 140)) bad++;
    }
    atomicAdd(&cnt, bad);
    __syncthreads();
    if (threadIdx.x == 0) *flag = (cnt > 1024) ? 1 : 0;
}

// ---------------------------------------------------------------------------
// Fused ingest (validated r5)
// ---------------------------------------------------------------------------
#define NSEG 24
struct IArgs {
    const void* src[NSEG];
    float* dst[NSEG];
    long start[NSEG + 1];
};

__global__ void ingest_all_k(IArgs a, const int* __restrict__ flag)
{
    long i = (long)blockIdx.x * 256 + threadIdx.x;
    if (i >= a.start[NSEG]) return;
    int s = 0;
#pragma unroll
    for (int j = 1; j < NSEG; j++) s += (i >= a.start[j]) ? 1 : 0;
    long idx = i - a.start[s];
    float v;
    if (*flag) v = ((const float*)a.src[s])[idx];
    else       v = __bfloat162float(((const bf16*)a.src[s])[idx]);
    a.dst[s][idx] = v;
}

// C[b][m][n] = bias[m] (or 0).  total = B*MN.
__global__ void fill_k(float* __restrict__ C, const float* __restrict__ bias,
                       long MN, int Nn, long total)
{
    long i = (long)blockIdx.x * 256 + threadIdx.x;
    if (i >= total) return;
    float v = 0.f;
    if (bias) {
        long r = i % MN;
        v = bias[(int)(r / Nn)];
    }
    C[i] = v;
}

// Tiled transpose: X[b][c][n] -> XT[b][n][c].  C=256. grid (N/32, 8, B), blk (32,8)
__global__ void tr_k(const float* __restrict__ X, float* __restrict__ XT, int N)
{
    __shared__ float t[32][33];
    int b = blockIdx.z, n0 = blockIdx.x * 32, c0 = blockIdx.y * 32;
    const float* Xb = X + (long)b * 256 * N;
    float* Tb = XT + (long)b * 256 * N;
    int tx = threadIdx.x, ty = threadIdx.y;
#pragma unroll
    for (int i = 0; i < 4; i++)
        t[ty + 8 * i][tx] = Xb[(long)(c0 + ty + 8 * i) * N + n0 + tx];
    __syncthreads();
#pragma unroll
    for (int i = 0; i < 4; i++)
        Tb[(long)(n0 + ty + 8 * i) * 256 + c0 + tx] = t[tx][ty + 8 * i];
}

// ---------------------------------------------------------------------------
// MFMA bf16 GEMM (validated r8/r9) — non-DCN ops.
// r12 lesson: everything feeding the offset conv stays PREC2 (offset-gain
// ~20x amplifies upstream bf16 error).
// ---------------------------------------------------------------------------
template <bool TRA, int BMODE, bool ACCUM, bool BIAS, int PREC, int KSPLIT>
__launch_bounds__(256)
__global__ void mgemm(const float* __restrict__ A, int lda, int ksA, long sA,
                      const void* __restrict__ Bsrc, int ldb, long sB,
                      float* __restrict__ C, int ldc, long sC,
                      const float* __restrict__ bias,
                      int M, int N, int K, int H, int wsh)
{
    __shared__ short As[PREC * 2560];
    __shared__ short Bs[PREC * 2560];

    const int bz = blockIdx.z;
    const float* Ab = A + (long)bz * sA;
    float* Cb = C + (long)bz * sC;
    const int mt = blockIdx.y / KSPLIT, ch = blockIdx.y % KSPLIT;
    const int m0 = mt * 64, n0 = blockIdx.x * 64;
    const int kchunk = K / KSPLIT;
    const int kbeg = ch * kchunk, kend = kbeg + kchunk;
    const int tid = threadIdx.x;

    f32x4 acc[2][2];
#pragma unroll
    for (int i = 0; i < 2; i++)
#pragma unroll
        for (int j = 0; j < 2; j++) acc[i][j] = (f32x4){0.f, 0.f, 0.f, 0.f};

    const int lane = tid & 63, wv = tid >> 6;
    const int moff = (wv & 1) * 32, noff = (wv >> 1) * 32;
    const int lr = lane & 15, lq = lane >> 4;
    const int mm = tid >> 2, kk0 = (tid & 3) * 8;
    const int nn = tid & 63, kg = tid >> 6;

    for (int k0 = kbeg; k0 < kend; k0 += 32) {
        // ---- stage A ----
        {
            float vv[8];
            if (m0 + mm < M) {
                if (!TRA) {
                    if (ksA == 1) {
                        const float4* s4 = (const float4*)(Ab + (long)(m0 + mm) * lda + k0 + kk0);
                        float4 v0 = s4[0], v1 = s4[1];
                        vv[0] = v0.x; vv[1] = v0.y; vv[2] = v0.z; vv[3] = v0.w;
                        vv[4] = v1.x; vv[5] = v1.y; vv[6] = v1.z; vv[7] = v1.w;
                    } else {
                        const float* s = Ab + (long)(m0 + mm) * lda + (long)(k0 + kk0) * ksA;
#pragma unroll
                        for (int j = 0; j < 8; j++) vv[j] = s[(long)j * ksA];
                    }
                } else {
#pragma unroll
                    for (int j = 0; j < 8; j++)
                        vv[j] = Ab[(long)(k0 + kk0 + j) * lda + m0 + mm];
                }
            } else {
#pragma unroll
                for (int j = 0; j < 8; j++) vv[j] = 0.f;
            }
            short8 hi, lo;
#pragma unroll
            for (int j = 0; j < 8; j++) { short h, l; splt(vv[j], h, l); hi[j] = h; lo[j] = l; }
            *(short8*)&As[mm * 40 + kk0] = hi;
            if (PREC == 2) *(short8*)&As[2560 + mm * 40 + kk0] = lo;
        }

        // ---- stage B ----
        if (BMODE == 1) {
            const float4* s4 = (const float4*)((const float*)Bsrc + (long)bz * sB +
                                               (long)(n0 + mm) * ldb + k0 + kk0);
            float4 v0 = s4[0], v1 = s4[1];
            float vv[8] = {v0.x, v0.y, v0.z, v0.w, v1.x, v1.y, v1.z, v1.w};
            short8 hi, lo;
#pragma unroll
            for (int j = 0; j < 8; j++) { short h, l; splt(vv[j], h, l); hi[j] = h; lo[j] = l; }
            int o = bsw(mm, tid & 3);
            *(short8*)&Bs[o] = hi;
            if (PREC == 2) *(short8*)&Bs[2560 + o] = lo;
        } else {
            float vv[8];
            if (BMODE == 0) {
#pragma unroll
                for (int j = 0; j < 8; j++)
                    vv[j] = ((const float*)Bsrc)[(long)bz * sB + (long)(k0 + kg * 8 + j) * ldb + n0 + nn];
            } else {  // BMODE 3: im2col
                int W = 1 << wsh;
                int n = n0 + nn;
                int hbase = n >> wsh, wbase = n & (W - 1);
#pragma unroll
                for (int j = 0; j < 8; j++) {
                    int kc = k0 + kg * 8 + j;
                    int c = kc / 9, tap = kc - 9 * c;
                    int h = hbase + tap / 3 - 1, w = wbase + tap % 3 - 1;
                    vv[j] = (h >= 0 && h < H && w >= 0 && w < W)
                          ? ((const float*)Bsrc)[(long)bz * sB + (long)c * ldb + (h << wsh) + w]
                          : 0.f;
                }
            }
            short8 hi, lo;
#pragma unroll
            for (int j = 0; j < 8; j++) { short h, l; splt(vv[j], h, l); hi[j] = h; lo[j] = l; }
            int o = bsw(nn, kg);
            *(short8*)&Bs[o] = hi;
            if (PREC == 2) *(short8*)&Bs[2560 + o] = lo;
        }
        __syncthreads();

        // ---- compute ----
        int rb0 = noff + lr, rb1 = noff + 16 + lr;
        short8 a0h = *(short8*)&As[(moff + lr) * 40 + lq * 8];
        short8 a1h = *(short8*)&As[(moff + 16 + lr) * 40 + lq * 8];
        short8 b0h = *(short8*)&Bs[bsw(rb0, lq)];
        short8 b1h = *(short8*)&Bs[bsw(rb1, lq)];
        acc[0][0] = __builtin_amdgcn_mfma_f32_16x16x32_bf16(a0h, b0h, acc[0][0], 0, 0, 0);
        acc[0][1] = __builtin_amdgcn_mfma_f32_16x16x32_bf16(a0h, b1h, acc[0][1], 0, 0, 0);
        acc[1][0] = __builtin_amdgcn_mfma_f32_16x16x32_bf16(a1h, b0h, acc[1][0], 0, 0, 0);
        acc[1][1] = __builtin_amdgcn_mfma_f32_16x16x32_bf16(a1h, b1h, acc[1][1], 0, 0, 0);
        if (PREC == 2) {
            short8 a0l = *(short8*)&As[2560 + (moff + lr) * 40 + lq * 8];
            short8 a1l = *(short8*)&As[2560 + (moff + 16 + lr) * 40 + lq * 8];
            short8 b0l = *(short8*)&Bs[2560 + bsw(rb0, lq)];
            short8 b1l = *(short8*)&Bs[2560 + bsw(rb1, lq)];
            acc[0][0] = __builtin_amdgcn_mfma_f32_16x16x32_bf16(a0h, b0l, acc[0][0], 0, 0, 0);
            acc[0][1] = __builtin_amdgcn_mfma_f32_16x16x32_bf16(a0h, b1l, acc[0][1], 0, 0, 0);
            acc[1][0] = __builtin_amdgcn_mfma_f32_16x16x32_bf16(a1h, b0l, acc[1][0], 0, 0, 0);
            acc[1][1] = __builtin_amdgcn_mfma_f32_16x16x32_bf16(a1h, b1l, acc[1][1], 0, 0, 0);
            acc[0][0] = __builtin_amdgcn_mfma_f32_16x16x32_bf16(a0l, b0h, acc[0][0], 0, 0, 0);
            acc[0][1] = __builtin_amdgcn_mfma_f32_16x16x32_bf16(a0l, b1h, acc[0][1], 0, 0, 0);
            acc[1][0] = __builtin_amdgcn_mfma_f32_16x16x32_bf16(a1l, b0h, acc[1][0], 0, 0, 0);
            acc[1][1] = __builtin_amdgcn_mfma_f32_16x16x32_bf16(a1l, b1h, acc[1][1], 0, 0, 0);
        }
        __syncthreads();
    }

    // ---- epilogue ----
#pragma unroll
    for (int mi = 0; mi < 2; mi++)
#pragma unroll
        for (int ni = 0; ni < 2; ni++) {
            int col = n0 + noff + ni * 16 + lr;
#pragma unroll
            for (int r = 0; r < 4; r++) {
                int row = m0 + moff + mi * 16 + lq * 4 + r;
                if (row < M) {
                    long o = (long)row * ldc + col;
                    float v = acc[mi][ni][r];
                    if (KSPLIT > 1) {
                        atomicAdd(&Cb[o], v);
                    } else {
                        if (BIAS) v += bias[row];
                        if (ACCUM) v += Cb[o];
                        Cb[o] = v;
                    }
                }
            }
        }
}

// ---------------------------------------------------------------------------
// DCN bilinear corner tables
// ---------------------------------------------------------------------------
__global__ void dcnw_k(const float* __restrict__ OO, float4* __restrict__ Tw,
                       int4* __restrict__ Ta, int N, int H, int W)
{
    long idx = (long)blockIdx.x * 256 + threadIdx.x;
    if (idx >= (long)16 * 9 * N) return;
    int b = (int)(idx / (9 * N));
    int r = (int)(idx % (9 * N));
    int tap = r / N, p = r % N;
    int h = p / W, w = p % W;
    const float* oob = OO + (long)b * 27 * N;
    float oy = oob[(2 * tap) * N + p];
    float ox = oob[(2 * tap + 1) * N + p];
    float mz = oob[(18 + tap) * N + p];
    float mask = 1.f / (1.f + expf(-mz));
    float y = (float)(h - 1 + tap / 3) + oy;
    float x = (float)(w - 1 + tap % 3) + ox;
    float y0 = floorf(y), x0 = floorf(x);
    float wy = y - y0, wx = x - x0;
    float ys[2] = {y0, y0 + 1.f};
    float xs[2] = {x0, x0 + 1.f};
    float wys[2] = {1.f - wy, wy};
    float wxs[2] = {1.f - wx, wx};
    float wv[4]; int av[4];
#pragma unroll
    for (int iy = 0; iy < 2; iy++)
#pragma unroll
        for (int ix = 0; ix < 2; ix++) {
            float yy = ys[iy], xx = xs[ix];
            bool valid = (yy >= 0.f) && (yy <= (float)(H - 1)) &&
                         (xx >= 0.f) && (xx <= (float)(W - 1));
            wv[iy * 2 + ix] = valid ? wys[iy] * wxs[ix] * mask : 0.f;
            int yc = (int)fminf(fmaxf(yy, 0.f), (float)(H - 1));
            int xc = (int)fminf(fmaxf(xx, 0.f), (float)(W - 1));
            av[iy * 2 + ix] = yc * W + xc;
        }
    Tw[idx] = (float4){wv[0], wv[1], wv[2], wv[3]};
    Ta[idx] = (int4){av[0], av[1], av[2], av[3]};
}

// ---------------------------------------------------------------------------
// DCN weight prepack (r19, validated): SINGLE-PLANE bf16,
// Wh[o][tap*256 + c], row stride 2304 shorts.
// ---------------------------------------------------------------------------
__global__ void wre4_k(const float* __restrict__ W, short* __restrict__ Wh)
{
    long idx = (long)blockIdx.x * 256 + threadIdx.x;
    if (idx >= 2304L * 256) return;
    int o = (int)(idx / 2304);
    int k = (int)(idx % 2304);
    int tap = k >> 8, c = k & 255;
    Wh[(long)o * 2304 + tap * 256 + c] = f2b(W[((long)o * 256 + c) * 9 + tap]);
}

// ---------------------------------------------------------------------------
// samp_k (r18, validated): WAVE-COALESCED gather.  4-lane group owns one n;
// lane cc2 reads float4 index q*4+cc2 of each corner row -> one contiguous
// 64B line per group per instruction.  Grid: (N/64, 9, B), blk 256.
// ---------------------------------------------------------------------------
__global__ void samp_k(const float4* __restrict__ Tw, const int4* __restrict__ Ta,
                       const float* __restrict__ XT, short* __restrict__ Si,
                       int N, int NRND)
{
    int tid = threadIdx.x;
    int g = tid >> 2, cc2 = tid & 3;
    int tap = blockIdx.y, b = blockIdx.z;
    int n = blockIdx.x * 64 + g;
    long ti = ((long)(b * 9 + tap)) * N + n;
    float4 w4 = Tw[ti];
    int4 a4 = Ta[ti];
    const float* Xb = XT + (long)b * 256 * N;
    const float4* r0 = (const float4*)(Xb + (long)a4.x * 256);
    const float4* r1 = (const float4*)(Xb + (long)a4.y * 256);
    const float4* r2 = (const float4*)(Xb + (long)a4.z * 256);
    const float4* r3 = (const float4*)(Xb + (long)a4.w * 256);
    long so = ((long)b * NRND + n) * 2304 + tap * 256;
    short4v out[16];
#pragma unroll
    for (int q = 0; q < 16; q++) {
        int i = q * 4 + cc2;
        float4 p = r0[i], qv = r1[i], s = r2[i], t = r3[i];
        out[q][0] = f2b(w4.x * p.x + w4.y * qv.x + w4.z * s.x + w4.w * t.x);
        out[q][1] = f2b(w4.x * p.y + w4.y * qv.y + w4.z * s.y + w4.w * t.y);
        out[q][2] = f2b(w4.x * p.z + w4.y * qv.z + w4.z * s.z + w4.w * t.z);
        out[q][3] = f2b(w4.x * p.w + w4.y * qv.w + w4.z * s.w + w4.w * t.w);
    }
#pragma unroll
    for (int q = 0; q < 16; q++)
        *(short4v*)&Si[so + q * 16 + cc2 * 4] = out[q];
}

// ---------------------------------------------------------------------------
// Deformable conv v11 (dcn9, r22, validated): fused template+search 1280-block
// dispatch, __launch_bounds__(256,4), 32-bit offsets, unroll 2.
// ---------------------------------------------------------------------------
__launch_bounds__(256, 4)
__global__ void dcn9_k(const short* __restrict__ Wh_s, const short* __restrict__ Si_s,
                       const short* __restrict__ Wh_t, const short* __restrict__ Si_t,
                       const float* __restrict__ bias_s, const float* __restrict__ bias_t,
                       float* __restrict__ Cs, float* __restrict__ Ct)
{
    __shared__ float red[8192];               // 2 slots x 64 fidx x 64 lanes

    int bid = blockIdx.x;
    const short* Wh; const short* Si; const float* bias; float* Cb;
    int N, mt, nt;
    if (bid < 1024) {                         // search: 16bz x 4mt x 16nt
        int bz = bid >> 6, t = bid & 63;
        mt = t >> 4; nt = t & 15;
        Wh = Wh_s; Si = Si_s + (long)bz * 1024 * 2304;
        bias = bias_s; Cb = Cs + (long)bz * 256 * 1024; N = 1024;
    } else {                                  // template: 16bz x 4mt x 4nt
        int r = bid - 1024;
        int bz = r >> 4, t = r & 15;
        mt = t >> 2; nt = t & 3;
        Wh = Wh_t; Si = Si_t + (long)bz * 256 * 2304;
        bias = bias_t; Cb = Ct + (long)bz * 256 * 256; N = 256;
    }
    const int m0 = mt * 64, n0 = nt * 64;

    const int tid = threadIdx.x;
    const int lane = tid & 63, wv = tid >> 6;
    const int lr = lane & 15, lq = lane >> 4;

    int aoff[4], boff[4];
#pragma unroll
    for (int mi = 0; mi < 4; mi++)
        aoff[mi] = (m0 + mi * 16 + lr) * 2304 + lq * 8;
#pragma unroll
    for (int ni = 0; ni < 4; ni++)
        boff[ni] = (n0 + ni * 16 + lr) * 2304 + lq * 8;

    f32x4 acc[4][4];
#pragma unroll
    for (int i = 0; i < 4; i++)
#pragma unroll
        for (int j = 0; j < 4; j++) acc[i][j] = (f32x4){0.f, 0.f, 0.f, 0.f};

    // ---- main loop: this wave's 18-kt K-chunk ----
    const int kbeg = wv * 18;
#pragma unroll 2
    for (int kt = kbeg; kt < kbeg + 18; kt++) {
        int koff = (kt >> 3) * 256 + (kt & 7) * 32;
        short8 ah[4], bh[4];
#pragma unroll
        for (int ni = 0; ni < 4; ni++)
            bh[ni] = *(const short8*)&Si[boff[ni] + koff];
#pragma unroll
        for (int mi = 0; mi < 4; mi++)
            ah[mi] = *(const short8*)&Wh[aoff[mi] + koff];
#pragma unroll
        for (int mi = 0; mi < 4; mi++)
#pragma unroll
            for (int ni = 0; ni < 4; ni++)
                acc[mi][ni] = __builtin_amdgcn_mfma_f32_16x16x32_bf16(ah[mi], bh[ni], acc[mi][ni], 0, 0, 0);
    }

    // ---- LDS tree reduction (lane-stride-4B layout: conflict-free b32) ----
    if (wv == 1 || wv == 3) {
        float* rp = &red[(wv == 1 ? 0 : 4096) + lane];
#pragma unroll
        for (int mi = 0; mi < 4; mi++)
#pragma unroll
            for (int ni = 0; ni < 4; ni++)
#pragma unroll
                for (int r2 = 0; r2 < 4; r2++)
                    rp[(mi * 16 + ni * 4 + r2) << 6] = acc[mi][ni][r2];
    }
    __syncthreads();
    if (wv == 0) {
        const float* rp = &red[lane];
#pragma unroll
        for (int mi = 0; mi < 4; mi++)
#pragma unroll
            for (int ni = 0; ni < 4; ni++)
#pragma unroll
                for (int r2 = 0; r2 < 4; r2++)
                    acc[mi][ni][r2] += rp[(mi * 16 + ni * 4 + r2) << 6];
    } else if (wv == 2) {
        float* rp = &red[4096 + lane];
#pragma unroll
        for (int mi = 0; mi < 4; mi++)
#pragma unroll
            for (int ni = 0; ni < 4; ni++)
#pragma unroll
                for (int r2 = 0; r2 < 4; r2++) {
                    int o = (mi * 16 + ni * 4 + r2) << 6;
                    float v = acc[mi][ni][r2] + rp[o];
                    rp[o] = v;
                }
    }
    __syncthreads();
    if (wv == 0) {
        const float* rp = &red[4096 + lane];
#pragma unroll
        for (int mi = 0; mi < 4; mi++)
#pragma unroll
            for (int ni = 0; ni < 4; ni++) {
                int col = n0 + ni * 16 + lr;
#pragma unroll
                for (int r2 = 0; r2 < 4; r2++) {
                    int row = m0 + mi * 16 + lq * 4 + r2;
                    float v = acc[mi][ni][r2] + rp[(mi * 16 + ni * 4 + r2) << 6];
                    Cb[(long)row * N + col] = v + bias[row];
                }
            }
    }
}

// Softmax over batch axis (16)
__global__ void softmax_b_k(float* __restrict__ att, long NN)
{
    long idx = (long)blockIdx.x * 256 + threadIdx.x;
    if (idx >= NN) return;
    float r[16];
    float mx = -1e30f;
#pragma unroll
    for (int b = 0; b < 16; b++) {
        r[b] = att[(long)b * NN + idx];
        mx = fmaxf(mx, r[b]);
    }
    float s = 0.f;
#pragma unroll
    for (int b = 0; b < 16; b++) { r[b] = expf(r[b] - mx); s += r[b]; }
    float inv = 1.f / s;
#pragma unroll
    for (int b = 0; b < 16; b++) att[(long)b * NN + idx] = r[b] * inv;
}

// M[b][c][d] = softmax_c(gram_t) + softmax_c(gram_s)
__global__ void gram_sm_k(const float* __restrict__ gt, const float* __restrict__ gs,
                          float* __restrict__ Mo)
{
    int b = blockIdx.x;
    int d = blockIdx.y * 64 + threadIdx.x;
    const float* gtb = gt + (long)b * 65536;
    const float* gsb = gs + (long)b * 65536;
    float* mb = Mo + (long)b * 65536;
    float mt = -1e30f, ms = -1e30f;
    for (int c = 0; c < 256; c++) {
        mt = fmaxf(mt, gtb[c * 256 + d]);
        ms = fmaxf(ms, gsb[c * 256 + d]);
    }
    float st = 0.f, ss = 0.f;
    for (int c = 0; c < 256; c++) {
        st += expf(gtb[c * 256 + d] - mt);
        ss += expf(gsb[c * 256 + d] - ms);
    }
    float it = 1.f / st, is = 1.f / ss;
    for (int c = 0; c < 256; c++)
        mb[c * 256 + d] = expf(gtb[c * 256 + d] - mt) * it +
                          expf(gsb[c * 256 + d] - ms) * is;
}

__global__ void cast_out_k(const float* __restrict__ t, const float* __restrict__ s,
                           void* __restrict__ out, long nt, long ntot,
                           const int* __restrict__ flag)
{
    long idx = (long)blockIdx.x * 256 + threadIdx.x;
    if (idx >= ntot) return;
    float v = (idx < nt) ? t[idx] : s[idx - nt];
    if (*flag) ((float*)out)[idx] = v;
    else       ((bf16*)out)[idx] = __float2bfloat16(v);
}

// ---------------------------------------------------------------------------
extern "C" void kernel_launch(void* const* d_in, const int* in_sizes, int n_in,
                              void* d_out, int out_size, void* d_ws, size_t ws_size,
                              hipStream_t stream)
{
    const int B = 16, C = 256;
    const int Nt = 256, Ns = 1024;
    const long sXt = (long)C * Nt, sXs = (long)C * Ns;
    dim3 blk(256);

    float* ws = (float*)d_ws;
    int* flag = (int*)d_ws;
    long off = 16;
    auto alloc = [&](long n) { float* p = ws + off; off += n; return p; };

    float* xt32     = alloc((long)B * C * Nt);
    float* xs32     = alloc((long)B * C * Ns);   // -> out_s_f32
    float* Wf       = alloc(1470464);
    float* q_t      = alloc((long)B * 32 * Nt);
    float* k_t      = alloc((long)B * 32 * Nt);
    float* v_t      = alloc((long)B * C * Nt);
    float* q_s      = alloc((long)B * 32 * Ns);
    float* k_s      = alloc((long)B * 32 * Ns);
    float* v_s      = alloc((long)B * C * Ns);   // -> DCN prep region
    float* gram_t   = alloc((long)B * C * C);    // -> out_t_f32
    float* gram_s   = alloc((long)B * C * C);
    float* Mc       = alloc((long)B * C * C);
    float* att_t    = alloc((long)B * Nt * Nt);  // xtT early / atT late
    float* att_slab = alloc((long)B * Ns * 256); // xsT early / asrT late
    float* at       = alloc((long)B * C * Nt);   // -> Si_t region late
    float* asr      = alloc((long)B * C * Ns);   // -> Si_t region late
    float* oo_t     = alloc((long)B * 27 * Nt);
    float* oo_s     = alloc((long)B * 27 * Ns);
    // Si region: full fp32 att (16.78M floats) during step 7, search Si later.
    float* Si_f     = alloc(18874368);
    short* Si = (short*)Si_f;
    float* att_full = Si_f;

    float* out_t_f32 = gram_t;
    float* out_s_f32 = xs32;
    float* xtT       = att_t;
    float* xsT       = att_slab;
    float* atT       = att_t;     // reuse after attention phases complete
    float* asrT      = att_slab;  // reuse after attention phases complete
    // Template Si lives in the dead at+asr region (needs 4.72M floats < 5.24M).
    short* Si_t = (short*)at;
    short* Wi_t = (short*)v_s;                   // 589824 shorts each (hi-only)
    short* Wi_s = (short*)v_s + 589824;
    float* tb   = v_s + 1179648;
    float4* Tw_t = (float4*)tb;
    int4*   Ta_t = (int4*)(tb + 147456);
    float4* Tw_s = (float4*)(tb + 2 * 147456);
    int4*   Ta_s = (int4*)(tb + 2 * 147456 + 589824);

    // ---- 0) detect + ingest ----
    detect_k<<<dim3(1), blk, 0, stream>>>((const unsigned short*)d_in[0], flag);
    long woff[22];
    {
        long acc = 0;
        for (int i = 2; i < 22; i++) { woff[i] = acc; acc += (in_sizes[i] + 7) & ~7L; }
    }
    IArgs ia;
    long tot = 0;
    auto seg = [&](int s, const void* src, float* dst, long n) {
        ia.src[s] = src; ia.dst[s] = dst; ia.start[s] = tot; tot += n;
    };
    seg(0, d_in[0], xt32, (long)B * C * Nt);
    seg(1, d_in[0], at,   (long)B * C * Nt);
    seg(2, d_in[1], xs32, (long)B * C * Ns);
    seg(3, d_in[1], asr,  (long)B * C * Ns);
    for (int i = 2; i < 22; i++) seg(2 + i, d_in[i], Wf + woff[i], in_sizes[i]);
    ia.start[NSEG] = tot;
    ingest_all_k<<<dim3((unsigned)((tot + 255) / 256)), blk, 0, stream>>>(ia, flag);

    const float *tq_w = Wf + woff[2],  *tq_b = Wf + woff[3];
    const float *tk_w = Wf + woff[4],  *tk_b = Wf + woff[5];
    const float *tv_w = Wf + woff[6],  *tv_b = Wf + woff[7];
    const float *sq_w = Wf + woff[8],  *sq_b = Wf + woff[9];
    const float *sk_w = Wf + woff[10], *sk_b = Wf + woff[11];
    const float *sv_w = Wf + woff[12], *sv_b = Wf + woff[13];
    const float *t_off_w = Wf + woff[14], *t_off_b = Wf + woff[15];
    const float *t_dcn_w = Wf + woff[16], *t_dcn_b = Wf + woff[17];
    const float *s_off_w = Wf + woff[18], *s_off_b = Wf + woff[19];
    const float *s_dcn_w = Wf + woff[20], *s_dcn_b = Wf + woff[21];

    // ---- 1) transposes + prefills ----
    tr_k<<<dim3(Nt / 32, 8, B), dim3(32, 8), 0, stream>>>(xt32, xtT, Nt);
    tr_k<<<dim3(Ns / 32, 8, B), dim3(32, 8), 0, stream>>>(xs32, xsT, Ns);
    fill_k<<<dim3((2 * B * C * C) / 256), blk, 0, stream>>>(gram_t, nullptr, 1, 1, 2L * B * C * C);
    fill_k<<<dim3((B * 27 * Nt + 255) / 256), blk, 0, stream>>>(oo_t, t_off_b, 27L * Nt, Nt, (long)B * 27 * Nt);
    fill_k<<<dim3((B * 27 * Ns + 255) / 256), blk, 0, stream>>>(oo_s, s_off_b, 27L * Ns, Ns, (long)B * 27 * Ns);

    // ---- 2) q,k,v projections (B = x^T, BMODE1, PREC2) ----
    mgemm<false, 1, false, true, 2, 1><<<dim3(Nt / 64, 1, B), blk, 0, stream>>>(
        tq_w, 256, 1, 0, xtT, 256, sXt, q_t, Nt, (long)32 * Nt, tq_b, 32, Nt, 256, 0, 0);
    mgemm<false, 1, false, true, 2, 1><<<dim3(Nt / 64, 1, B), blk, 0, stream>>>(
        tk_w, 256, 1, 0, xtT, 256, sXt, k_t, Nt, (long)32 * Nt, tk_b, 32, Nt, 256, 0, 0);
    mgemm<false, 1, false, true, 2, 1><<<dim3(Nt / 64, 4, B), blk, 0, stream>>>(
        tv_w, 256, 1, 0, xtT, 256, sXt, v_t, Nt, sXt, tv_b, 256, Nt, 256, 0, 0);
    mgemm<false, 1, false, true, 2, 1><<<dim3(Ns / 64, 1, B), blk, 0, stream>>>(
        sq_w, 256, 1, 0, xsT, 256, sXs, q_s, Ns, (long)32 * Ns, sq_b, 32, Ns, 256, 0, 0);
    mgemm<false, 1, false, true, 2, 1><<<dim3(Ns / 64, 1, B), blk, 0, stream>>>(
        sk_w, 256, 1, 0, xsT, 256, sXs, k_s, Ns, (long)32 * Ns, sk_b, 32, Ns, 256, 0, 0);
    mgemm<false, 1, false, true, 2, 1><<<dim3(Ns / 64, 4, B), blk, 0, stream>>>(
        sv_w, 256, 1, 0, xsT, 256, sXs, v_s, Ns, sXs, sv_b, 256, Ns, 256, 0, 0);

    // ---- 3) gram matrices (BMODE1, K-split 4, PREC1 — validated since r0) ----
    mgemm<false, 1, false, false, 1, 4><<<dim3(4, 16, B), blk, 0, stream>>>(
        xt32, Nt, 1, sXt, xt32, Nt, sXt, gram_t, 256, (long)C * C, nullptr, 256, 256, Nt, 0, 0);
    mgemm<false, 1, false, false, 1, 4><<<dim3(4, 16, B), blk, 0, stream>>>(
        xs32, Ns, 1, sXs, xs32, Ns, sXs, gram_s, 256, (long)C * C, nullptr, 256, 256, Ns, 0, 0);

    // ---- 4) M ----
    gram_sm_k<<<dim3(B, 4), dim3(64), 0, stream>>>(gram_t, gram_s, Mc);

    // ---- 5) channel attention (B = x^T, BMODE1, PREC2) ----
    mgemm<false, 1, true, false, 2, 2><<<dim3(Nt / 64, 8, B), blk, 0, stream>>>(
        Mc, 256, 1, (long)C * C, xtT, 256, sXt, at, Nt, sXt, nullptr, 256, Nt, 256, 0, 0);
    mgemm<false, 1, true, false, 2, 1><<<dim3(Ns / 64, 4, B), blk, 0, stream>>>(
        Mc, 256, 1, (long)C * C, xsT, 256, sXs, asr, Ns, sXs, nullptr, 256, Ns, 256, 0, 0);

    // ---- 6) template spatial attention (PREC2) ----
    mgemm<true, 0, false, false, 2, 1><<<dim3(4, 4, B), blk, 0, stream>>>(
        k_t, Nt, 1, (long)32 * Nt, q_t, Nt, (long)32 * Nt, att_t, Nt, (long)Nt * Nt,
        nullptr, Nt, Nt, 32, 0, 0);
    softmax_b_k<<<dim3((Nt * Nt) / 256), blk, 0, stream>>>(att_t, (long)Nt * Nt);
    mgemm<false, 1, true, false, 2, 2><<<dim3(Nt / 64, 8, B), blk, 0, stream>>>(
        v_t, Nt, 1, sXt, att_t, Nt, (long)Nt * Nt, at, Nt, sXt, nullptr, 256, Nt, Nt, 0, 0);

    // ---- 7) search spatial attention — FULL WIDTH (r23): att_full lives in
    // the Si region (dead until step 10).  One QK, one softmax, one PV with
    // KSPLIT=1 + ACCUM (zero atomics) replace 12 slabbed dispatches with
    // ~16.8M atomicAdds.  Same fp32 accumulation; K-order change only. ----
    mgemm<true, 0, false, false, 2, 1><<<dim3(Ns / 64, Ns / 64, B), blk, 0, stream>>>(
        k_s, Ns, 1, (long)32 * Ns, q_s, Ns, (long)32 * Ns,
        att_full, Ns, (long)Ns * Ns, nullptr, Ns, Ns, 32, 0, 0);
    softmax_b_k<<<dim3((unsigned)(((long)Ns * Ns) / 256)), blk, 0, stream>>>(
        att_full, (long)Ns * Ns);
    mgemm<false, 1, true, false, 2, 1><<<dim3(Ns / 64, 4, B), blk, 0, stream>>>(
        v_s, Ns, 1, sXs, att_full, Ns, (long)Ns * Ns,
        asr, Ns, sXs, nullptr, 256, Ns, Ns, 0, 0);

    // ---- 8) offset convs (im2col, K-split 4, PREC2) ----
    mgemm<false, 3, false, false, 2, 4><<<dim3(Nt / 64, 4, B), blk, 0, stream>>>(
        t_off_w, 2304, 1, 0, at, Nt, sXt, oo_t, Nt, (long)27 * Nt,
        nullptr, 27, Nt, 2304, 16, 4);
    mgemm<false, 3, false, false, 2, 4><<<dim3(Ns / 64, 4, B), blk, 0, stream>>>(
        s_off_w, 2304, 1, 0, asr, Ns, sXs, oo_s, Ns, (long)27 * Ns,
        nullptr, 27, Ns, 2304, 32, 5);

    // ---- 9) DCN prep (v_s region dead; att_t/att_slab dead after step 7) ----
    wre4_k<<<dim3((2304 * 256) / 256), blk, 0, stream>>>(t_dcn_w, Wi_t);
    wre4_k<<<dim3((2304 * 256) / 256), blk, 0, stream>>>(s_dcn_w, Wi_s);
    dcnw_k<<<dim3((B * 9 * Nt) / 256), blk, 0, stream>>>(oo_t, Tw_t, Ta_t, Nt, 16, 16);
    dcnw_k<<<dim3((B * 9 * Ns) / 256), blk, 0, stream>>>(oo_s, Tw_s, Ta_s, Ns, 32, 32);
    // transpose attention outputs to [n][c] for channel-contiguous sampling
    tr_k<<<dim3(Nt / 32, 8, B), dim3(32, 8), 0, stream>>>(at, atT, Nt);
    tr_k<<<dim3(Ns / 32, 8, B), dim3(32, 8), 0, stream>>>(asr, asrT, Ns);

    // ---- 10) deformable convs: sample both, then ONE fused 1280-block GEMM ----
    samp_k<<<dim3(Nt / 64, 9, B), blk, 0, stream>>>(Tw_t, Ta_t, atT, Si_t, Nt, 256);
    samp_k<<<dim3(Ns / 64, 9, B), blk, 0, stream>>>(Tw_s, Ta_s, asrT, Si, Ns, 1024);
    dcn9_k<<<dim3(1280), blk, 0, stream>>>(Wi_s, Si, Wi_t, Si_t,
                                           s_dcn_b, t_dcn_b, out_s_f32, out_t_f32);

    // ---- 11) emit output ----
    long nt = (long)B * C * Nt;
    long ntot = nt + (long)B * C * Ns;
    cast_out_k<<<dim3((unsigned)((ntot + 255) / 256)), blk, 0, stream>>>(
        out_t_f32, out_s_f32, d_out, nt, ntot, flag);
}

// Round 15
// 720.597 us; speedup vs baseline: 1.1420x; 1.0219x over previous
//
#include <hip/hip_runtime.h>
#include <hip/hip_bf16.h>

typedef __hip_bfloat16 bf16;
typedef __attribute__((ext_vector_type(8))) short short8;
typedef __attribute__((ext_vector_type(4))) short short4v;
typedef __attribute__((ext_vector_type(4))) float f32x4;

__device__ __forceinline__ short f2b(float v)
{
    union { bf16 b; short s; } u;
    u.b = __float2bfloat16(v);
    return u.s;
}
__device__ __forceinline__ float b2f(short s)
{
    union { short s; bf16 b; } u;
    u.s = s;
    return __bfloat162float(u.b);
}
__device__ __forceinline__ void splt(float v, short& hi, short& lo)
{
    hi = f2b(v);
    lo = f2b(v - b2f(hi));
}
__device__ __forceinline__ int bsw(int row, int g)
{
    return row * 40 + (((g + (row >> 3)) & 3) << 3);
}

// ---------------------------------------------------------------------------
// Dtype detector (validated r2): flag=1 -> fp32 storage, 0 -> bf16.
// ---------------------------------------------------------------------------
__global__ void detect_k(const unsigned short* __restrict__ p, int* __restrict__ flag)
{
    __shared__ int cnt;
    if (threadIdx.x == 0) cnt = 0;
    __syncthreads();
    int bad = 0;
    for (int i = threadIdx.x; i < 4096; i += 256) {
        unsigned short u = p[2 * i];
        int e = (u >> 7) & 0xFF;
        if (e != 0 && (e < 100 || e > 140)) bad++;
    }
    atomicAdd(&cnt, bad);
    __syncthreads();
    if (threadIdx.x == 0) *flag = (cnt > 1024) ? 1 : 0;
}

// ---------------------------------------------------------------------------
// Fused ingest (validated r5)
// ---------------------------------------------------------------------------
#define NSEG 24
struct IArgs {
    const void* src[NSEG];
    float* dst[NSEG];
    long start[NSEG + 1];
};

__global__ void ingest_all_k(IArgs a, const int* __restrict__ flag)
{
    long i = (long)blockIdx.x * 256 + threadIdx.x;
    if (i >= a.start[NSEG]) return;
    int s = 0;
#pragma unroll
    for (int j = 1; j < NSEG; j++) s += (i >= a.start[j]) ? 1 : 0;
    long idx = i - a.start[s];
    float v;
    if (*flag) v = ((const float*)a.src[s])[idx];
    else       v = __bfloat162float(((const bf16*)a.src[s])[idx]);
    a.dst[s][idx] = v;
}

// C[b][m][n] = bias[m] (or 0).  total = B*MN.
__global__ void fill_k(float* __restrict__ C, const float* __restrict__ bias,
                       long MN, int Nn, long total)
{
    long i = (long)blockIdx.x * 256 + threadIdx.x;
    if (i >= total) return;
    float v = 0.f;
    if (bias) {
        long r = i % MN;
        v = bias[(int)(r / Nn)];
    }
    C[i] = v;
}

// Merged bias-prefill for the two offset-conv outputs (r24 launch merge).
__global__ void fillo_k(float* __restrict__ C1, const float* __restrict__ b1,
                        int N1, long tot1,
                        float* __restrict__ C2, const float* __restrict__ b2,
                        int N2, long tot2)
{
    long i = (long)blockIdx.x * 256 + threadIdx.x;
    if (i < tot1) {
        long r = i % ((long)27 * N1);
        C1[i] = b1[(int)(r / N1)];
    } else {
        i -= tot1;
        if (i < tot2) {
            long r = i % ((long)27 * N2);
            C2[i] = b2[(int)(r / N2)];
        }
    }
}

// Merged tiled transpose pair (r24): X[b][c][n] -> XT[b][n][c] for two
// tensors in one dispatch.  grid ((N1+N2)/32, 8, B), blk (32,8).
__global__ void tr2_k(const float* __restrict__ X1, float* __restrict__ T1, int N1,
                      const float* __restrict__ X2, float* __restrict__ T2, int N2)
{
    __shared__ float t[32][33];
    int bx = blockIdx.x;
    const float* X; float* T; int N, n0;
    int nb1 = N1 / 32;
    if (bx < nb1) { X = X1; T = T1; N = N1; n0 = bx * 32; }
    else          { X = X2; T = T2; N = N2; n0 = (bx - nb1) * 32; }
    int b = blockIdx.z, c0 = blockIdx.y * 32;
    const float* Xb = X + (long)b * 256 * N;
    float* Tb = T + (long)b * 256 * N;
    int tx = threadIdx.x, ty = threadIdx.y;
#pragma unroll
    for (int i = 0; i < 4; i++)
        t[ty + 8 * i][tx] = Xb[(long)(c0 + ty + 8 * i) * N + n0 + tx];
    __syncthreads();
#pragma unroll
    for (int i = 0; i < 4; i++)
        Tb[(long)(n0 + ty + 8 * i) * 256 + c0 + tx] = t[tx][ty + 8 * i];
}

// ---------------------------------------------------------------------------
// MFMA bf16 GEMM (validated r8/r9) — non-DCN ops.
// r12 lesson: everything feeding the offset conv stays PREC2 (offset-gain
// ~20x amplifies upstream bf16 error).
// ---------------------------------------------------------------------------
template <bool TRA, int BMODE, bool ACCUM, bool BIAS, int PREC, int KSPLIT>
__launch_bounds__(256)
__global__ void mgemm(const float* __restrict__ A, int lda, int ksA, long sA,
                      const void* __restrict__ Bsrc, int ldb, long sB,
                      float* __restrict__ C, int ldc, long sC,
                      const float* __restrict__ bias,
                      int M, int N, int K, int H, int wsh)
{
    __shared__ short As[PREC * 2560];
    __shared__ short Bs[PREC * 2560];

    const int bz = blockIdx.z;
    const float* Ab = A + (long)bz * sA;
    float* Cb = C + (long)bz * sC;
    const int mt = blockIdx.y / KSPLIT, ch = blockIdx.y % KSPLIT;
    const int m0 = mt * 64, n0 = blockIdx.x * 64;
    const int kchunk = K / KSPLIT;
    const int kbeg = ch * kchunk, kend = kbeg + kchunk;
    const int tid = threadIdx.x;

    f32x4 acc[2][2];
#pragma unroll
    for (int i = 0; i < 2; i++)
#pragma unroll
        for (int j = 0; j < 2; j++) acc[i][j] = (f32x4){0.f, 0.f, 0.f, 0.f};

    const int lane = tid & 63, wv = tid >> 6;
    const int moff = (wv & 1) * 32, noff = (wv >> 1) * 32;
    const int lr = lane & 15, lq = lane >> 4;
    const int mm = tid >> 2, kk0 = (tid & 3) * 8;
    const int nn = tid & 63, kg = tid >> 6;

    for (int k0 = kbeg; k0 < kend; k0 += 32) {
        // ---- stage A ----
        {
            float vv[8];
            if (m0 + mm < M) {
                if (!TRA) {
                    if (ksA == 1) {
                        const float4* s4 = (const float4*)(Ab + (long)(m0 + mm) * lda + k0 + kk0);
                        float4 v0 = s4[0], v1 = s4[1];
                        vv[0] = v0.x; vv[1] = v0.y; vv[2] = v0.z; vv[3] = v0.w;
                        vv[4] = v1.x; vv[5] = v1.y; vv[6] = v1.z; vv[7] = v1.w;
                    } else {
                        const float* s = Ab + (long)(m0 + mm) * lda + (long)(k0 + kk0) * ksA;
#pragma unroll
                        for (int j = 0; j < 8; j++) vv[j] = s[(long)j * ksA];
                    }
                } else {
#pragma unroll
                    for (int j = 0; j < 8; j++)
                        vv[j] = Ab[(long)(k0 + kk0 + j) * lda + m0 + mm];
                }
            } else {
#pragma unroll
                for (int j = 0; j < 8; j++) vv[j] = 0.f;
            }
            short8 hi, lo;
#pragma unroll
            for (int j = 0; j < 8; j++) { short h, l; splt(vv[j], h, l); hi[j] = h; lo[j] = l; }
            *(short8*)&As[mm * 40 + kk0] = hi;
            if (PREC == 2) *(short8*)&As[2560 + mm * 40 + kk0] = lo;
        }

        // ---- stage B ----
        if (BMODE == 1) {
            const float4* s4 = (const float4*)((const float*)Bsrc + (long)bz * sB +
                                               (long)(n0 + mm) * ldb + k0 + kk0);
            float4 v0 = s4[0], v1 = s4[1];
            float vv[8] = {v0.x, v0.y, v0.z, v0.w, v1.x, v1.y, v1.z, v1.w};
            short8 hi, lo;
#pragma unroll
            for (int j = 0; j < 8; j++) { short h, l; splt(vv[j], h, l); hi[j] = h; lo[j] = l; }
            int o = bsw(mm, tid & 3);
            *(short8*)&Bs[o] = hi;
            if (PREC == 2) *(short8*)&Bs[2560 + o] = lo;
        } else {
            float vv[8];
            if (BMODE == 0) {
#pragma unroll
                for (int j = 0; j < 8; j++)
                    vv[j] = ((const float*)Bsrc)[(long)bz * sB + (long)(k0 + kg * 8 + j) * ldb + n0 + nn];
            } else {  // BMODE 3: im2col
                int W = 1 << wsh;
                int n = n0 + nn;
                int hbase = n >> wsh, wbase = n & (W - 1);
#pragma unroll
                for (int j = 0; j < 8; j++) {
                    int kc = k0 + kg * 8 + j;
                    int c = kc / 9, tap = kc - 9 * c;
                    int h = hbase + tap / 3 - 1, w = wbase + tap % 3 - 1;
                    vv[j] = (h >= 0 && h < H && w >= 0 && w < W)
                          ? ((const float*)Bsrc)[(long)bz * sB + (long)c * ldb + (h << wsh) + w]
                          : 0.f;
                }
            }
            short8 hi, lo;
#pragma unroll
            for (int j = 0; j < 8; j++) { short h, l; splt(vv[j], h, l); hi[j] = h; lo[j] = l; }
            int o = bsw(nn, kg);
            *(short8*)&Bs[o] = hi;
            if (PREC == 2) *(short8*)&Bs[2560 + o] = lo;
        }
        __syncthreads();

        // ---- compute ----
        int rb0 = noff + lr, rb1 = noff + 16 + lr;
        short8 a0h = *(short8*)&As[(moff + lr) * 40 + lq * 8];
        short8 a1h = *(short8*)&As[(moff + 16 + lr) * 40 + lq * 8];
        short8 b0h = *(short8*)&Bs[bsw(rb0, lq)];
        short8 b1h = *(short8*)&Bs[bsw(rb1, lq)];
        acc[0][0] = __builtin_amdgcn_mfma_f32_16x16x32_bf16(a0h, b0h, acc[0][0], 0, 0, 0);
        acc[0][1] = __builtin_amdgcn_mfma_f32_16x16x32_bf16(a0h, b1h, acc[0][1], 0, 0, 0);
        acc[1][0] = __builtin_amdgcn_mfma_f32_16x16x32_bf16(a1h, b0h, acc[1][0], 0, 0, 0);
        acc[1][1] = __builtin_amdgcn_mfma_f32_16x16x32_bf16(a1h, b1h, acc[1][1], 0, 0, 0);
        if (PREC == 2) {
            short8 a0l = *(short8*)&As[2560 + (moff + lr) * 40 + lq * 8];
            short8 a1l = *(short8*)&As[2560 + (moff + 16 + lr) * 40 + lq * 8];
            short8 b0l = *(short8*)&Bs[2560 + bsw(rb0, lq)];
            short8 b1l = *(short8*)&Bs[2560 + bsw(rb1, lq)];
            acc[0][0] = __builtin_amdgcn_mfma_f32_16x16x32_bf16(a0h, b0l, acc[0][0], 0, 0, 0);
            acc[0][1] = __builtin_amdgcn_mfma_f32_16x16x32_bf16(a0h, b1l, acc[0][1], 0, 0, 0);
            acc[1][0] = __builtin_amdgcn_mfma_f32_16x16x32_bf16(a1h, b0l, acc[1][0], 0, 0, 0);
            acc[1][1] = __builtin_amdgcn_mfma_f32_16x16x32_bf16(a1h, b1l, acc[1][1], 0, 0, 0);
            acc[0][0] = __builtin_amdgcn_mfma_f32_16x16x32_bf16(a0l, b0h, acc[0][0], 0, 0, 0);
            acc[0][1] = __builtin_amdgcn_mfma_f32_16x16x32_bf16(a0l, b1h, acc[0][1], 0, 0, 0);
            acc[1][0] = __builtin_amdgcn_mfma_f32_16x16x32_bf16(a1l, b0h, acc[1][0], 0, 0, 0);
            acc[1][1] = __builtin_amdgcn_mfma_f32_16x16x32_bf16(a1l, b1h, acc[1][1], 0, 0, 0);
        }
        __syncthreads();
    }

    // ---- epilogue ----
#pragma unroll
    for (int mi = 0; mi < 2; mi++)
#pragma unroll
        for (int ni = 0; ni < 2; ni++) {
            int col = n0 + noff + ni * 16 + lr;
#pragma unroll
            for (int r = 0; r < 4; r++) {
                int row = m0 + moff + mi * 16 + lq * 4 + r;
                if (row < M) {
                    long o = (long)row * ldc + col;
                    float v = acc[mi][ni][r];
                    if (KSPLIT > 1) {
                        atomicAdd(&Cb[o], v);
                    } else {
                        if (BIAS) v += bias[row];
                        if (ACCUM) v += Cb[o];
                        Cb[o] = v;
                    }
                }
            }
        }
}

// ---------------------------------------------------------------------------
// DCN bilinear corner tables — merged template+search (r24).
// idx < 16*9*256 -> template (H=W=16); else search (H=W=32).
// ---------------------------------------------------------------------------
__global__ void dcnw2_k(const float* __restrict__ OOt, float4* __restrict__ Twt,
                        int4* __restrict__ Tat,
                        const float* __restrict__ OOs, float4* __restrict__ Tws,
                        int4* __restrict__ Tas)
{
    long idx = (long)blockIdx.x * 256 + threadIdx.x;
    const long n1 = 16L * 9 * 256;
    const long n2 = 16L * 9 * 1024;
    const float* OO; float4* Tw; int4* Ta; int N, H, W;
    if (idx < n1) { OO = OOt; Tw = Twt; Ta = Tat; N = 256; H = 16; W = 16; }
    else {
        idx -= n1;
        if (idx >= n2) return;
        OO = OOs; Tw = Tws; Ta = Tas; N = 1024; H = 32; W = 32;
    }
    int b = (int)(idx / (9 * N));
    int r = (int)(idx % (9 * N));
    int tap = r / N, p = r % N;
    int h = p / W, w = p % W;
    const float* oob = OO + (long)b * 27 * N;
    float oy = oob[(2 * tap) * N + p];
    float ox = oob[(2 * tap + 1) * N + p];
    float mz = oob[(18 + tap) * N + p];
    float mask = 1.f / (1.f + expf(-mz));
    float y = (float)(h - 1 + tap / 3) + oy;
    float x = (float)(w - 1 + tap % 3) + ox;
    float y0 = floorf(y), x0 = floorf(x);
    float wy = y - y0, wx = x - x0;
    float ys[2] = {y0, y0 + 1.f};
    float xs[2] = {x0, x0 + 1.f};
    float wys[2] = {1.f - wy, wy};
    float wxs[2] = {1.f - wx, wx};
    float wv[4]; int av[4];
#pragma unroll
    for (int iy = 0; iy < 2; iy++)
#pragma unroll
        for (int ix = 0; ix < 2; ix++) {
            float yy = ys[iy], xx = xs[ix];
            bool valid = (yy >= 0.f) && (yy <= (float)(H - 1)) &&
                         (xx >= 0.f) && (xx <= (float)(W - 1));
            wv[iy * 2 + ix] = valid ? wys[iy] * wxs[ix] * mask : 0.f;
            int yc = (int)fminf(fmaxf(yy, 0.f), (float)(H - 1));
            int xc = (int)fminf(fmaxf(xx, 0.f), (float)(W - 1));
            av[iy * 2 + ix] = yc * W + xc;
        }
    long o = (long)(b * 9 + tap) * N + p;
    Tw[o] = (float4){wv[0], wv[1], wv[2], wv[3]};
    Ta[o] = (int4){av[0], av[1], av[2], av[3]};
}

// ---------------------------------------------------------------------------
// DCN weight prepack — merged template+search (r24).  SINGLE-PLANE bf16,
// Wh[o][tap*256 + c], row stride 2304 shorts.  grid 4608 blocks.
// ---------------------------------------------------------------------------
__global__ void wre5_k(const float* __restrict__ Wt, short* __restrict__ Wht,
                       const float* __restrict__ Ws, short* __restrict__ Whs)
{
    long idx = (long)blockIdx.x * 256 + threadIdx.x;
    const long half = 2304L * 256;
    const float* W; short* Wh;
    if (idx < half) { W = Wt; Wh = Wht; }
    else            { W = Ws; Wh = Whs; idx -= half; }
    int o = (int)(idx / 2304);
    int k = (int)(idx % 2304);
    int tap = k >> 8, c = k & 255;
    Wh[(long)o * 2304 + tap * 256 + c] = f2b(W[((long)o * 256 + c) * 9 + tap]);
}

// ---------------------------------------------------------------------------
// samp2_k — merged template+search wave-coalesced gather (r24).
// 4-lane group owns one n; lane cc2 reads float4 index q*4+cc2 of each
// corner row -> one contiguous 64B line per group per instruction.
// Grid: (4+16, 9, 16); bx<4 -> template.
// ---------------------------------------------------------------------------
__global__ void samp2_k(const float4* __restrict__ Twt, const int4* __restrict__ Tat,
                        const float* __restrict__ XTt, short* __restrict__ Sit,
                        const float4* __restrict__ Tws, const int4* __restrict__ Tas,
                        const float* __restrict__ XTs, short* __restrict__ Sis)
{
    int bx = blockIdx.x;
    const float4* Tw; const int4* Ta; const float* XT; short* Si;
    int N, NRND, nblk;
    if (bx < 4) { Tw = Twt; Ta = Tat; XT = XTt; Si = Sit; N = 256;  NRND = 256;  nblk = bx; }
    else        { Tw = Tws; Ta = Tas; XT = XTs; Si = Sis; N = 1024; NRND = 1024; nblk = bx - 4; }

    int tid = threadIdx.x;
    int g = tid >> 2, cc2 = tid & 3;
    int tap = blockIdx.y, b = blockIdx.z;
    int n = nblk * 64 + g;
    long ti = ((long)(b * 9 + tap)) * N + n;
    float4 w4 = Tw[ti];
    int4 a4 = Ta[ti];
    const float* Xb = XT + (long)b * 256 * N;
    const float4* r0 = (const float4*)(Xb + (long)a4.x * 256);
    const float4* r1 = (const float4*)(Xb + (long)a4.y * 256);
    const float4* r2 = (const float4*)(Xb + (long)a4.z * 256);
    const float4* r3 = (const float4*)(Xb + (long)a4.w * 256);
    long so = ((long)b * NRND + n) * 2304 + tap * 256;
    short4v out[16];
#pragma unroll
    for (int q = 0; q < 16; q++) {
        int i = q * 4 + cc2;
        float4 p = r0[i], qv = r1[i], s = r2[i], t = r3[i];
        out[q][0] = f2b(w4.x * p.x + w4.y * qv.x + w4.z * s.x + w4.w * t.x);
        out[q][1] = f2b(w4.x * p.y + w4.y * qv.y + w4.z * s.y + w4.w * t.y);
        out[q][2] = f2b(w4.x * p.z + w4.y * qv.z + w4.z * s.z + w4.w * t.z);
        out[q][3] = f2b(w4.x * p.w + w4.y * qv.w + w4.z * s.w + w4.w * t.w);
    }
#pragma unroll
    for (int q = 0; q < 16; q++)
        *(short4v*)&Si[so + q * 16 + cc2 * 4] = out[q];
}

// ---------------------------------------------------------------------------
// Deformable conv v11 (dcn9, r22, validated): fused template+search 1280-block
// dispatch, __launch_bounds__(256,4), 32-bit offsets, unroll 2.
// ---------------------------------------------------------------------------
__launch_bounds__(256, 4)
__global__ void dcn9_k(const short* __restrict__ Wh_s, const short* __restrict__ Si_s,
                       const short* __restrict__ Wh_t, const short* __restrict__ Si_t,
                       const float* __restrict__ bias_s, const float* __restrict__ bias_t,
                       float* __restrict__ Cs, float* __restrict__ Ct)
{
    __shared__ float red[8192];               // 2 slots x 64 fidx x 64 lanes

    int bid = blockIdx.x;
    const short* Wh; const short* Si; const float* bias; float* Cb;
    int N, mt, nt;
    if (bid < 1024) {                         // search: 16bz x 4mt x 16nt
        int bz = bid >> 6, t = bid & 63;
        mt = t >> 4; nt = t & 15;
        Wh = Wh_s; Si = Si_s + (long)bz * 1024 * 2304;
        bias = bias_s; Cb = Cs + (long)bz * 256 * 1024; N = 1024;
    } else {                                  // template: 16bz x 4mt x 4nt
        int r = bid - 1024;
        int bz = r >> 4, t = r & 15;
        mt = t >> 2; nt = t & 3;
        Wh = Wh_t; Si = Si_t + (long)bz * 256 * 2304;
        bias = bias_t; Cb = Ct + (long)bz * 256 * 256; N = 256;
    }
    const int m0 = mt * 64, n0 = nt * 64;

    const int tid = threadIdx.x;
    const int lane = tid & 63, wv = tid >> 6;
    const int lr = lane & 15, lq = lane >> 4;

    int aoff[4], boff[4];
#pragma unroll
    for (int mi = 0; mi < 4; mi++)
        aoff[mi] = (m0 + mi * 16 + lr) * 2304 + lq * 8;
#pragma unroll
    for (int ni = 0; ni < 4; ni++)
        boff[ni] = (n0 + ni * 16 + lr) * 2304 + lq * 8;

    f32x4 acc[4][4];
#pragma unroll
    for (int i = 0; i < 4; i++)
#pragma unroll
        for (int j = 0; j < 4; j++) acc[i][j] = (f32x4){0.f, 0.f, 0.f, 0.f};

    // ---- main loop: this wave's 18-kt K-chunk ----
    const int kbeg = wv * 18;
#pragma unroll 2
    for (int kt = kbeg; kt < kbeg + 18; kt++) {
        int koff = (kt >> 3) * 256 + (kt & 7) * 32;
        short8 ah[4], bh[4];
#pragma unroll
        for (int ni = 0; ni < 4; ni++)
            bh[ni] = *(const short8*)&Si[boff[ni] + koff];
#pragma unroll
        for (int mi = 0; mi < 4; mi++)
            ah[mi] = *(const short8*)&Wh[aoff[mi] + koff];
#pragma unroll
        for (int mi = 0; mi < 4; mi++)
#pragma unroll
            for (int ni = 0; ni < 4; ni++)
                acc[mi][ni] = __builtin_amdgcn_mfma_f32_16x16x32_bf16(ah[mi], bh[ni], acc[mi][ni], 0, 0, 0);
    }

    // ---- LDS tree reduction (lane-stride-4B layout: conflict-free b32) ----
    if (wv == 1 || wv == 3) {
        float* rp = &red[(wv == 1 ? 0 : 4096) + lane];
#pragma unroll
        for (int mi = 0; mi < 4; mi++)
#pragma unroll
            for (int ni = 0; ni < 4; ni++)
#pragma unroll
                for (int r2 = 0; r2 < 4; r2++)
                    rp[(mi * 16 + ni * 4 + r2) << 6] = acc[mi][ni][r2];
    }
    __syncthreads();
    if (wv == 0) {
        const float* rp = &red[lane];
#pragma unroll
        for (int mi = 0; mi < 4; mi++)
#pragma unroll
            for (int ni = 0; ni < 4; ni++)
#pragma unroll
                for (int r2 = 0; r2 < 4; r2++)
                    acc[mi][ni][r2] += rp[(mi * 16 + ni * 4 + r2) << 6];
    } else if (wv == 2) {
        float* rp = &red[4096 + lane];
#pragma unroll
        for (int mi = 0; mi < 4; mi++)
#pragma unroll
            for (int ni = 0; ni < 4; ni++)
#pragma unroll
                for (int r2 = 0; r2 < 4; r2++) {
                    int o = (mi * 16 + ni * 4 + r2) << 6;
                    float v = acc[mi][ni][r2] + rp[o];
                    rp[o] = v;
                }
    }
    __syncthreads();
    if (wv == 0) {
        const float* rp = &red[4096 + lane];
#pragma unroll
        for (int mi = 0; mi < 4; mi++)
#pragma unroll
            for (int ni = 0; ni < 4; ni++) {
                int col = n0 + ni * 16 + lr;
#pragma unroll
                for (int r2 = 0; r2 < 4; r2++) {
                    int row = m0 + mi * 16 + lq * 4 + r2;
                    float v = acc[mi][ni][r2] + rp[(mi * 16 + ni * 4 + r2) << 6];
                    Cb[(long)row * N + col] = v + bias[row];
                }
            }
    }
}

// Softmax over batch axis (16)
__global__ void softmax_b_k(float* __restrict__ att, long NN)
{
    long idx = (long)blockIdx.x * 256 + threadIdx.x;
    if (idx >= NN) return;
    float r[16];
    float mx = -1e30f;
#pragma unroll
    for (int b = 0; b < 16; b++) {
        r[b] = att[(long)b * NN + idx];
        mx = fmaxf(mx, r[b]);
    }
    float s = 0.f;
#pragma unroll
    for (int b = 0; b < 16; b++) { r[b] = expf(r[b] - mx); s += r[b]; }
    float inv = 1.f / s;
#pragma unroll
    for (int b = 0; b < 16; b++) att[(long)b * NN + idx] = r[b] * inv;
}

// M[b][c][d] = softmax_c(gram_t) + softmax_c(gram_s)
__global__ void gram_sm_k(const float* __restrict__ gt, const float* __restrict__ gs,
                          float* __restrict__ Mo)
{
    int b = blockIdx.x;
    int d = blockIdx.y * 64 + threadIdx.x;
    const float* gtb = gt + (long)b * 65536;
    const float* gsb = gs + (long)b * 65536;
    float* mb = Mo + (long)b * 65536;
    float mt = -1e30f, ms = -1e30f;
    for (int c = 0; c < 256; c++) {
        mt = fmaxf(mt, gtb[c * 256 + d]);
        ms = fmaxf(ms, gsb[c * 256 + d]);
    }
    float st = 0.f, ss = 0.f;
    for (int c = 0; c < 256; c++) {
        st += expf(gtb[c * 256 + d] - mt);
        ss += expf(gsb[c * 256 + d] - ms);
    }
    float it = 1.f / st, is = 1.f / ss;
    for (int c = 0; c < 256; c++)
        mb[c * 256 + d] = expf(gtb[c * 256 + d] - mt) * it +
                          expf(gsb[c * 256 + d] - ms) * is;
}

__global__ void cast_out_k(const float* __restrict__ t, const float* __restrict__ s,
                           void* __restrict__ out, long nt, long ntot,
                           const int* __restrict__ flag)
{
    long idx = (long)blockIdx.x * 256 + threadIdx.x;
    if (idx >= ntot) return;
    float v = (idx < nt) ? t[idx] : s[idx - nt];
    if (*flag) ((float*)out)[idx] = v;
    else       ((bf16*)out)[idx] = __float2bfloat16(v);
}

// ---------------------------------------------------------------------------
extern "C" void kernel_launch(void* const* d_in, const int* in_sizes, int n_in,
                              void* d_out, int out_size, void* d_ws, size_t ws_size,
                              hipStream_t stream)
{
    const int B = 16, C = 256;
    const int Nt = 256, Ns = 1024;
    const long sXt = (long)C * Nt, sXs = (long)C * Ns;
    dim3 blk(256);

    float* ws = (float*)d_ws;
    int* flag = (int*)d_ws;
    long off = 16;
    auto alloc = [&](long n) { float* p = ws + off; off += n; return p; };

    float* xt32     = alloc((long)B * C * Nt);
    float* xs32     = alloc((long)B * C * Ns);   // -> out_s_f32
    float* Wf       = alloc(1470464);
    float* q_t      = alloc((long)B * 32 * Nt);
    float* k_t      = alloc((long)B * 32 * Nt);
    float* v_t      = alloc((long)B * C * Nt);
    float* q_s      = alloc((long)B * 32 * Ns);
    float* k_s      = alloc((long)B * 32 * Ns);
    float* v_s      = alloc((long)B * C * Ns);   // -> DCN prep region
    float* gram_t   = alloc((long)B * C * C);    // -> out_t_f32
    float* gram_s   = alloc((long)B * C * C);
    float* Mc       = alloc((long)B * C * C);
    float* att_t    = alloc((long)B * Nt * Nt);  // xtT early / atT late
    float* att_slab = alloc((long)B * Ns * 256); // xsT early / asrT late
    float* at       = alloc((long)B * C * Nt);   // -> Si_t region late
    float* asr      = alloc((long)B * C * Ns);   // -> Si_t region late
    float* oo_t     = alloc((long)B * 27 * Nt);
    float* oo_s     = alloc((long)B * 27 * Ns);
    // Si region: full fp32 att (16.78M floats) during step 7, search Si later.
    float* Si_f     = alloc(18874368);
    short* Si = (short*)Si_f;
    float* att_full = Si_f;

    float* out_t_f32 = gram_t;
    float* out_s_f32 = xs32;
    float* xtT       = att_t;
    float* xsT       = att_slab;
    float* atT       = att_t;     // reuse after attention phases complete
    float* asrT      = att_slab;  // reuse after attention phases complete
    // Template Si lives in the dead at+asr region (needs 4.72M floats < 5.24M).
    short* Si_t = (short*)at;
    short* Wi_t = (short*)v_s;                   // 589824 shorts each (hi-only)
    short* Wi_s = (short*)v_s + 589824;
    float* tb   = v_s + 1179648;
    float4* Tw_t = (float4*)tb;
    int4*   Ta_t = (int4*)(tb + 147456);
    float4* Tw_s = (float4*)(tb + 2 * 147456);
    int4*   Ta_s = (int4*)(tb + 2 * 147456 + 589824);

    // ---- 0) detect + ingest ----
    detect_k<<<dim3(1), blk, 0, stream>>>((const unsigned short*)d_in[0], flag);
    long woff[22];
    {
        long acc = 0;
        for (int i = 2; i < 22; i++) { woff[i] = acc; acc += (in_sizes[i] + 7) & ~7L; }
    }
    IArgs ia;
    long tot = 0;
    auto seg = [&](int s, const void* src, float* dst, long n) {
        ia.src[s] = src; ia.dst[s] = dst; ia.start[s] = tot; tot += n;
    };
    seg(0, d_in[0], xt32, (long)B * C * Nt);
    seg(1, d_in[0], at,   (long)B * C * Nt);
    seg(2, d_in[1], xs32, (long)B * C * Ns);
    seg(3, d_in[1], asr,  (long)B * C * Ns);
    for (int i = 2; i < 22; i++) seg(2 + i, d_in[i], Wf + woff[i], in_sizes[i]);
    ia.start[NSEG] = tot;
    ingest_all_k<<<dim3((unsigned)((tot + 255) / 256)), blk, 0, stream>>>(ia, flag);

    const float *tq_w = Wf + woff[2],  *tq_b = Wf + woff[3];
    const float *tk_w = Wf + woff[4],  *tk_b = Wf + woff[5];
    const float *tv_w = Wf + woff[6],  *tv_b = Wf + woff[7];
    const float *sq_w = Wf + woff[8],  *sq_b = Wf + woff[9];
    const float *sk_w = Wf + woff[10], *sk_b = Wf + woff[11];
    const float *sv_w = Wf + woff[12], *sv_b = Wf + woff[13];
    const float *t_off_w = Wf + woff[14], *t_off_b = Wf + woff[15];
    const float *t_dcn_w = Wf + woff[16], *t_dcn_b = Wf + woff[17];
    const float *s_off_w = Wf + woff[18], *s_off_b = Wf + woff[19];
    const float *s_dcn_w = Wf + woff[20], *s_dcn_b = Wf + woff[21];

    // ---- 1) transposes (merged) + prefills (merged) ----
    tr2_k<<<dim3((Nt + Ns) / 32, 8, B), dim3(32, 8), 0, stream>>>(
        xt32, xtT, Nt, xs32, xsT, Ns);
    fill_k<<<dim3((2 * B * C * C) / 256), blk, 0, stream>>>(gram_t, nullptr, 1, 1, 2L * B * C * C);
    fillo_k<<<dim3((unsigned)((B * 27L * (Nt + Ns) + 255) / 256)), blk, 0, stream>>>(
        oo_t, t_off_b, Nt, (long)B * 27 * Nt,
        oo_s, s_off_b, Ns, (long)B * 27 * Ns);

    // ---- 2) q,k,v projections (B = x^T, BMODE1, PREC2) ----
    mgemm<false, 1, false, true, 2, 1><<<dim3(Nt / 64, 1, B), blk, 0, stream>>>(
        tq_w, 256, 1, 0, xtT, 256, sXt, q_t, Nt, (long)32 * Nt, tq_b, 32, Nt, 256, 0, 0);
    mgemm<false, 1, false, true, 2, 1><<<dim3(Nt / 64, 1, B), blk, 0, stream>>>(
        tk_w, 256, 1, 0, xtT, 256, sXt, k_t, Nt, (long)32 * Nt, tk_b, 32, Nt, 256, 0, 0);
    mgemm<false, 1, false, true, 2, 1><<<dim3(Nt / 64, 4, B), blk, 0, stream>>>(
        tv_w, 256, 1, 0, xtT, 256, sXt, v_t, Nt, sXt, tv_b, 256, Nt, 256, 0, 0);
    mgemm<false, 1, false, true, 2, 1><<<dim3(Ns / 64, 1, B), blk, 0, stream>>>(
        sq_w, 256, 1, 0, xsT, 256, sXs, q_s, Ns, (long)32 * Ns, sq_b, 32, Ns, 256, 0, 0);
    mgemm<false, 1, false, true, 2, 1><<<dim3(Ns / 64, 1, B), blk, 0, stream>>>(
        sk_w, 256, 1, 0, xsT, 256, sXs, k_s, Ns, (long)32 * Ns, sk_b, 32, Ns, 256, 0, 0);
    mgemm<false, 1, false, true, 2, 1><<<dim3(Ns / 64, 4, B), blk, 0, stream>>>(
        sv_w, 256, 1, 0, xsT, 256, sXs, v_s, Ns, sXs, sv_b, 256, Ns, 256, 0, 0);

    // ---- 3) gram matrices (BMODE1, K-split 4, PREC1 — validated since r0) ----
    mgemm<false, 1, false, false, 1, 4><<<dim3(4, 16, B), blk, 0, stream>>>(
        xt32, Nt, 1, sXt, xt32, Nt, sXt, gram_t, 256, (long)C * C, nullptr, 256, 256, Nt, 0, 0);
    mgemm<false, 1, false, false, 1, 4><<<dim3(4, 16, B), blk, 0, stream>>>(
        xs32, Ns, 1, sXs, xs32, Ns, sXs, gram_s, 256, (long)C * C, nullptr, 256, 256, Ns, 0, 0);

    // ---- 4) M ----
    gram_sm_k<<<dim3(B, 4), dim3(64), 0, stream>>>(gram_t, gram_s, Mc);

    // ---- 5) channel attention (B = x^T, BMODE1, PREC2) ----
    mgemm<false, 1, true, false, 2, 2><<<dim3(Nt / 64, 8, B), blk, 0, stream>>>(
        Mc, 256, 1, (long)C * C, xtT, 256, sXt, at, Nt, sXt, nullptr, 256, Nt, 256, 0, 0);
    mgemm<false, 1, true, false, 2, 1><<<dim3(Ns / 64, 4, B), blk, 0, stream>>>(
        Mc, 256, 1, (long)C * C, xsT, 256, sXs, asr, Ns, sXs, nullptr, 256, Ns, 256, 0, 0);

    // ---- 6) template spatial attention (PREC2) ----
    mgemm<true, 0, false, false, 2, 1><<<dim3(4, 4, B), blk, 0, stream>>>(
        k_t, Nt, 1, (long)32 * Nt, q_t, Nt, (long)32 * Nt, att_t, Nt, (long)Nt * Nt,
        nullptr, Nt, Nt, 32, 0, 0);
    softmax_b_k<<<dim3((Nt * Nt) / 256), blk, 0, stream>>>(att_t, (long)Nt * Nt);
    mgemm<false, 1, true, false, 2, 2><<<dim3(Nt / 64, 8, B), blk, 0, stream>>>(
        v_t, Nt, 1, sXt, att_t, Nt, (long)Nt * Nt, at, Nt, sXt, nullptr, 256, Nt, Nt, 0, 0);

    // ---- 7) search spatial attention — FULL WIDTH (r23, validated) ----
    mgemm<true, 0, false, false, 2, 1><<<dim3(Ns / 64, Ns / 64, B), blk, 0, stream>>>(
        k_s, Ns, 1, (long)32 * Ns, q_s, Ns, (long)32 * Ns,
        att_full, Ns, (long)Ns * Ns, nullptr, Ns, Ns, 32, 0, 0);
    softmax_b_k<<<dim3((unsigned)(((long)Ns * Ns) / 256)), blk, 0, stream>>>(
        att_full, (long)Ns * Ns);
    mgemm<false, 1, true, false, 2, 1><<<dim3(Ns / 64, 4, B), blk, 0, stream>>>(
        v_s, Ns, 1, sXs, att_full, Ns, (long)Ns * Ns,
        asr, Ns, sXs, nullptr, 256, Ns, Ns, 0, 0);

    // ---- 8) offset convs (im2col, K-split 4, PREC2) ----
    mgemm<false, 3, false, false, 2, 4><<<dim3(Nt / 64, 4, B), blk, 0, stream>>>(
        t_off_w, 2304, 1, 0, at, Nt, sXt, oo_t, Nt, (long)27 * Nt,
        nullptr, 27, Nt, 2304, 16, 4);
    mgemm<false, 3, false, false, 2, 4><<<dim3(Ns / 64, 4, B), blk, 0, stream>>>(
        s_off_w, 2304, 1, 0, asr, Ns, sXs, oo_s, Ns, (long)27 * Ns,
        nullptr, 27, Ns, 2304, 32, 5);

    // ---- 9) DCN prep (merged dispatches, r24) ----
    wre5_k<<<dim3(4608), blk, 0, stream>>>(t_dcn_w, Wi_t, s_dcn_w, Wi_s);
    dcnw2_k<<<dim3((unsigned)((16L * 9 * (Nt + Ns)) / 256)), blk, 0, stream>>>(
        oo_t, Tw_t, Ta_t, oo_s, Tw_s, Ta_s);
    // transpose attention outputs to [n][c] for channel-contiguous sampling
    tr2_k<<<dim3((Nt + Ns) / 32, 8, B), dim3(32, 8), 0, stream>>>(
        at, atT, Nt, asr, asrT, Ns);

    // ---- 10) deformable convs: merged sampler + ONE fused 1280-block GEMM ----
    samp2_k<<<dim3(20, 9, B), blk, 0, stream>>>(
        Tw_t, Ta_t, atT, Si_t, Tw_s, Ta_s, asrT, Si);
    dcn9_k<<<dim3(1280), blk, 0, stream>>>(Wi_s, Si, Wi_t, Si_t,
                                           s_dcn_b, t_dcn_b, out_s_f32, out_t_f32);

    // ---- 11) emit output ----
    long nt = (long)B * C * Nt;
    long ntot = nt + (long)B * C * Ns;
    cast_out_k<<<dim3((unsigned)((ntot + 255) / 256)), blk, 0, stream>>>(
        out_t_f32, out_s_f32, d_out, nt, ntot, flag);
}

// Round 16
// 638.828 us; speedup vs baseline: 1.2882x; 1.1280x over previous
//
#include <hip/hip_runtime.h>
#include <hip/hip_bf16.h>

typedef __hip_bfloat16 bf16;
typedef __attribute__((ext_vector_type(8))) short short8;
typedef __attribute__((ext_vector_type(4))) short short4v;
typedef __attribute__((ext_vector_type(4))) float f32x4;

__device__ __forceinline__ short f2b(float v)
{
    union { bf16 b; short s; } u;
    u.b = __float2bfloat16(v);
    return u.s;
}
__device__ __forceinline__ float b2f(short s)
{
    union { short s; bf16 b; } u;
    u.s = s;
    return __bfloat162float(u.b);
}
__device__ __forceinline__ void splt(float v, short& hi, short& lo)
{
    hi = f2b(v);
    lo = f2b(v - b2f(hi));
}
__device__ __forceinline__ int bsw(int row, int g)
{
    return row * 40 + (((g + (row >> 3)) & 3) << 3);
}

// ---------------------------------------------------------------------------
// Dtype detector (validated r2): flag=1 -> fp32 storage, 0 -> bf16.
// ---------------------------------------------------------------------------
__global__ void detect_k(const unsigned short* __restrict__ p, int* __restrict__ flag)
{
    __shared__ int cnt;
    if (threadIdx.x == 0) cnt = 0;
    __syncthreads();
    int bad = 0;
    for (int i = threadIdx.x; i < 4096; i += 256) {
        unsigned short u = p[2 * i];
        int e = (u >> 7) & 0xFF;
        if (e != 0 && (e < 100 || e > 140)) bad++;
    }
    atomicAdd(&cnt, bad);
    __syncthreads();
    if (threadIdx.x == 0) *flag = (cnt > 1024) ? 1 : 0;
}

// ---------------------------------------------------------------------------
// Fused ingest (validated r5)
// ---------------------------------------------------------------------------
#define NSEG 24
struct IArgs {
    const void* src[NSEG];
    float* dst[NSEG];
    long start[NSEG + 1];
};

__global__ void ingest_all_k(IArgs a, const int* __restrict__ flag)
{
    long i = (long)blockIdx.x * 256 + threadIdx.x;
    if (i >= a.start[NSEG]) return;
    int s = 0;
#pragma unroll
    for (int j = 1; j < NSEG; j++) s += (i >= a.start[j]) ? 1 : 0;
    long idx = i - a.start[s];
    float v;
    if (*flag) v = ((const float*)a.src[s])[idx];
    else       v = __bfloat162float(((const bf16*)a.src[s])[idx]);
    a.dst[s][idx] = v;
}

// C[b][m][n] = bias[m] (or 0).  total = B*MN.
__global__ void fill_k(float* __restrict__ C, const float* __restrict__ bias,
                       long MN, int Nn, long total)
{
    long i = (long)blockIdx.x * 256 + threadIdx.x;
    if (i >= total) return;
    float v = 0.f;
    if (bias) {
        long r = i % MN;
        v = bias[(int)(r / Nn)];
    }
    C[i] = v;
}

// Merged bias-prefill for the two offset-conv outputs (r24 launch merge).
__global__ void fillo_k(float* __restrict__ C1, const float* __restrict__ b1,
                        int N1, long tot1,
                        float* __restrict__ C2, const float* __restrict__ b2,
                        int N2, long tot2)
{
    long i = (long)blockIdx.x * 256 + threadIdx.x;
    if (i < tot1) {
        long r = i % ((long)27 * N1);
        C1[i] = b1[(int)(r / N1)];
    } else {
        i -= tot1;
        if (i < tot2) {
            long r = i % ((long)27 * N2);
            C2[i] = b2[(int)(r / N2)];
        }
    }
}

// Merged tiled transpose pair (r24): X[b][c][n] -> XT[b][n][c] for two
// tensors in one dispatch.  grid ((N1+N2)/32, 8, B), blk (32,8).
__global__ void tr2_k(const float* __restrict__ X1, float* __restrict__ T1, int N1,
                      const float* __restrict__ X2, float* __restrict__ T2, int N2)
{
    __shared__ float t[32][33];
    int bx = blockIdx.x;
    const float* X; float* T; int N, n0;
    int nb1 = N1 / 32;
    if (bx < nb1) { X = X1; T = T1; N = N1; n0 = bx * 32; }
    else          { X = X2; T = T2; N = N2; n0 = (bx - nb1) * 32; }
    int b = blockIdx.z, c0 = blockIdx.y * 32;
    const float* Xb = X + (long)b * 256 * N;
    float* Tb = T + (long)b * 256 * N;
    int tx = threadIdx.x, ty = threadIdx.y;
#pragma unroll
    for (int i = 0; i < 4; i++)
        t[ty + 8 * i][tx] = Xb[(long)(c0 + ty + 8 * i) * N + n0 + tx];
    __syncthreads();
#pragma unroll
    for (int i = 0; i < 4; i++)
        Tb[(long)(n0 + ty + 8 * i) * 256 + c0 + tx] = t[tx][ty + 8 * i];
}

// ---------------------------------------------------------------------------
// MFMA bf16 GEMM (validated r8/r9) — non-DCN ops.
// r12 lesson: everything feeding the offset conv stays PREC2 (offset-gain
// ~20x amplifies upstream bf16 error).
// ---------------------------------------------------------------------------
template <bool TRA, int BMODE, bool ACCUM, bool BIAS, int PREC, int KSPLIT>
__launch_bounds__(256)
__global__ void mgemm(const float* __restrict__ A, int lda, int ksA, long sA,
                      const void* __restrict__ Bsrc, int ldb, long sB,
                      float* __restrict__ C, int ldc, long sC,
                      const float* __restrict__ bias,
                      int M, int N, int K, int H, int wsh)
{
    __shared__ short As[PREC * 2560];
    __shared__ short Bs[PREC * 2560];

    const int bz = blockIdx.z;
    const float* Ab = A + (long)bz * sA;
    float* Cb = C + (long)bz * sC;
    const int mt = blockIdx.y / KSPLIT, ch = blockIdx.y % KSPLIT;
    const int m0 = mt * 64, n0 = blockIdx.x * 64;
    const int kchunk = K / KSPLIT;
    const int kbeg = ch * kchunk, kend = kbeg + kchunk;
    const int tid = threadIdx.x;

    f32x4 acc[2][2];
#pragma unroll
    for (int i = 0; i < 2; i++)
#pragma unroll
        for (int j = 0; j < 2; j++) acc[i][j] = (f32x4){0.f, 0.f, 0.f, 0.f};

    const int lane = tid & 63, wv = tid >> 6;
    const int moff = (wv & 1) * 32, noff = (wv >> 1) * 32;
    const int lr = lane & 15, lq = lane >> 4;
    const int mm = tid >> 2, kk0 = (tid & 3) * 8;
    const int nn = tid & 63, kg = tid >> 6;

    for (int k0 = kbeg; k0 < kend; k0 += 32) {
        // ---- stage A ----
        {
            float vv[8];
            if (m0 + mm < M) {
                if (!TRA) {
                    if (ksA == 1) {
                        const float4* s4 = (const float4*)(Ab + (long)(m0 + mm) * lda + k0 + kk0);
                        float4 v0 = s4[0], v1 = s4[1];
                        vv[0] = v0.x; vv[1] = v0.y; vv[2] = v0.z; vv[3] = v0.w;
                        vv[4] = v1.x; vv[5] = v1.y; vv[6] = v1.z; vv[7] = v1.w;
                    } else {
                        const float* s = Ab + (long)(m0 + mm) * lda + (long)(k0 + kk0) * ksA;
#pragma unroll
                        for (int j = 0; j < 8; j++) vv[j] = s[(long)j * ksA];
                    }
                } else {
#pragma unroll
                    for (int j = 0; j < 8; j++)
                        vv[j] = Ab[(long)(k0 + kk0 + j) * lda + m0 + mm];
                }
            } else {
#pragma unroll
                for (int j = 0; j < 8; j++) vv[j] = 0.f;
            }
            short8 hi, lo;
#pragma unroll
            for (int j = 0; j < 8; j++) { short h, l; splt(vv[j], h, l); hi[j] = h; lo[j] = l; }
            *(short8*)&As[mm * 40 + kk0] = hi;
            if (PREC == 2) *(short8*)&As[2560 + mm * 40 + kk0] = lo;
        }

        // ---- stage B ----
        if (BMODE == 1) {
            const float4* s4 = (const float4*)((const float*)Bsrc + (long)bz * sB +
                                               (long)(n0 + mm) * ldb + k0 + kk0);
            float4 v0 = s4[0], v1 = s4[1];
            float vv[8] = {v0.x, v0.y, v0.z, v0.w, v1.x, v1.y, v1.z, v1.w};
            short8 hi, lo;
#pragma unroll
            for (int j = 0; j < 8; j++) { short h, l; splt(vv[j], h, l); hi[j] = h; lo[j] = l; }
            int o = bsw(mm, tid & 3);
            *(short8*)&Bs[o] = hi;
            if (PREC == 2) *(short8*)&Bs[2560 + o] = lo;
        } else {
            float vv[8];
            if (BMODE == 0) {
#pragma unroll
                for (int j = 0; j < 8; j++)
                    vv[j] = ((const float*)Bsrc)[(long)bz * sB + (long)(k0 + kg * 8 + j) * ldb + n0 + nn];
            } else {  // BMODE 3: im2col
                int W = 1 << wsh;
                int n = n0 + nn;
                int hbase = n >> wsh, wbase = n & (W - 1);
#pragma unroll
                for (int j = 0; j < 8; j++) {
                    int kc = k0 + kg * 8 + j;
                    int c = kc / 9, tap = kc - 9 * c;
                    int h = hbase + tap / 3 - 1, w = wbase + tap % 3 - 1;
                    vv[j] = (h >= 0 && h < H && w >= 0 && w < W)
                          ? ((const float*)Bsrc)[(long)bz * sB + (long)c * ldb + (h << wsh) + w]
                          : 0.f;
                }
            }
            short8 hi, lo;
#pragma unroll
            for (int j = 0; j < 8; j++) { short h, l; splt(vv[j], h, l); hi[j] = h; lo[j] = l; }
            int o = bsw(nn, kg);
            *(short8*)&Bs[o] = hi;
            if (PREC == 2) *(short8*)&Bs[2560 + o] = lo;
        }
        __syncthreads();

        // ---- compute ----
        int rb0 = noff + lr, rb1 = noff + 16 + lr;
        short8 a0h = *(short8*)&As[(moff + lr) * 40 + lq * 8];
        short8 a1h = *(short8*)&As[(moff + 16 + lr) * 40 + lq * 8];
        short8 b0h = *(short8*)&Bs[bsw(rb0, lq)];
        short8 b1h = *(short8*)&Bs[bsw(rb1, lq)];
        acc[0][0] = __builtin_amdgcn_mfma_f32_16x16x32_bf16(a0h, b0h, acc[0][0], 0, 0, 0);
        acc[0][1] = __builtin_amdgcn_mfma_f32_16x16x32_bf16(a0h, b1h, acc[0][1], 0, 0, 0);
        acc[1][0] = __builtin_amdgcn_mfma_f32_16x16x32_bf16(a1h, b0h, acc[1][0], 0, 0, 0);
        acc[1][1] = __builtin_amdgcn_mfma_f32_16x16x32_bf16(a1h, b1h, acc[1][1], 0, 0, 0);
        if (PREC == 2) {
            short8 a0l = *(short8*)&As[2560 + (moff + lr) * 40 + lq * 8];
            short8 a1l = *(short8*)&As[2560 + (moff + 16 + lr) * 40 + lq * 8];
            short8 b0l = *(short8*)&Bs[2560 + bsw(rb0, lq)];
            short8 b1l = *(short8*)&Bs[2560 + bsw(rb1, lq)];
            acc[0][0] = __builtin_amdgcn_mfma_f32_16x16x32_bf16(a0h, b0l, acc[0][0], 0, 0, 0);
            acc[0][1] = __builtin_amdgcn_mfma_f32_16x16x32_bf16(a0h, b1l, acc[0][1], 0, 0, 0);
            acc[1][0] = __builtin_amdgcn_mfma_f32_16x16x32_bf16(a1h, b0l, acc[1][0], 0, 0, 0);
            acc[1][1] = __builtin_amdgcn_mfma_f32_16x16x32_bf16(a1h, b1l, acc[1][1], 0, 0, 0);
            acc[0][0] = __builtin_amdgcn_mfma_f32_16x16x32_bf16(a0l, b0h, acc[0][0], 0, 0, 0);
            acc[0][1] = __builtin_amdgcn_mfma_f32_16x16x32_bf16(a0l, b1h, acc[0][1], 0, 0, 0);
            acc[1][0] = __builtin_amdgcn_mfma_f32_16x16x32_bf16(a1l, b0h, acc[1][0], 0, 0, 0);
            acc[1][1] = __builtin_amdgcn_mfma_f32_16x16x32_bf16(a1l, b1h, acc[1][1], 0, 0, 0);
        }
        __syncthreads();
    }

    // ---- epilogue ----
#pragma unroll
    for (int mi = 0; mi < 2; mi++)
#pragma unroll
        for (int ni = 0; ni < 2; ni++) {
            int col = n0 + noff + ni * 16 + lr;
#pragma unroll
            for (int r = 0; r < 4; r++) {
                int row = m0 + moff + mi * 16 + lq * 4 + r;
                if (row < M) {
                    long o = (long)row * ldc + col;
                    float v = acc[mi][ni][r];
                    if (KSPLIT > 1) {
                        atomicAdd(&Cb[o], v);
                    } else {
                        if (BIAS) v += bias[row];
                        if (ACCUM) v += Cb[o];
                        Cb[o] = v;
                    }
                }
            }
        }
}

// ---------------------------------------------------------------------------
// DCN bilinear corner tables — merged template+search (r24).
// ---------------------------------------------------------------------------
__global__ void dcnw2_k(const float* __restrict__ OOt, float4* __restrict__ Twt,
                        int4* __restrict__ Tat,
                        const float* __restrict__ OOs, float4* __restrict__ Tws,
                        int4* __restrict__ Tas)
{
    long idx = (long)blockIdx.x * 256 + threadIdx.x;
    const long n1 = 16L * 9 * 256;
    const long n2 = 16L * 9 * 1024;
    const float* OO; float4* Tw; int4* Ta; int N, H, W;
    if (idx < n1) { OO = OOt; Tw = Twt; Ta = Tat; N = 256; H = 16; W = 16; }
    else {
        idx -= n1;
        if (idx >= n2) return;
        OO = OOs; Tw = Tws; Ta = Tas; N = 1024; H = 32; W = 32;
    }
    int b = (int)(idx / (9 * N));
    int r = (int)(idx % (9 * N));
    int tap = r / N, p = r % N;
    int h = p / W, w = p % W;
    const float* oob = OO + (long)b * 27 * N;
    float oy = oob[(2 * tap) * N + p];
    float ox = oob[(2 * tap + 1) * N + p];
    float mz = oob[(18 + tap) * N + p];
    float mask = 1.f / (1.f + expf(-mz));
    float y = (float)(h - 1 + tap / 3) + oy;
    float x = (float)(w - 1 + tap % 3) + ox;
    float y0 = floorf(y), x0 = floorf(x);
    float wy = y - y0, wx = x - x0;
    float ys[2] = {y0, y0 + 1.f};
    float xs[2] = {x0, x0 + 1.f};
    float wys[2] = {1.f - wy, wy};
    float wxs[2] = {1.f - wx, wx};
    float wv[4]; int av[4];
#pragma unroll
    for (int iy = 0; iy < 2; iy++)
#pragma unroll
        for (int ix = 0; ix < 2; ix++) {
            float yy = ys[iy], xx = xs[ix];
            bool valid = (yy >= 0.f) && (yy <= (float)(H - 1)) &&
                         (xx >= 0.f) && (xx <= (float)(W - 1));
            wv[iy * 2 + ix] = valid ? wys[iy] * wxs[ix] * mask : 0.f;
            int yc = (int)fminf(fmaxf(yy, 0.f), (float)(H - 1));
            int xc = (int)fminf(fmaxf(xx, 0.f), (float)(W - 1));
            av[iy * 2 + ix] = yc * W + xc;
        }
    long o = (long)(b * 9 + tap) * N + p;
    Tw[o] = (float4){wv[0], wv[1], wv[2], wv[3]};
    Ta[o] = (int4){av[0], av[1], av[2], av[3]};
}

// ---------------------------------------------------------------------------
// DCN weight prepack — merged template+search (r24).
// ---------------------------------------------------------------------------
__global__ void wre5_k(const float* __restrict__ Wt, short* __restrict__ Wht,
                       const float* __restrict__ Ws, short* __restrict__ Whs)
{
    long idx = (long)blockIdx.x * 256 + threadIdx.x;
    const long half = 2304L * 256;
    const float* W; short* Wh;
    if (idx < half) { W = Wt; Wh = Wht; }
    else            { W = Ws; Wh = Whs; idx -= half; }
    int o = (int)(idx / 2304);
    int k = (int)(idx % 2304);
    int tap = k >> 8, c = k & 255;
    Wh[(long)o * 2304 + tap * 256 + c] = f2b(W[((long)o * 256 + c) * 9 + tap]);
}

// ---------------------------------------------------------------------------
// samp2_k — merged template+search wave-coalesced gather (r24, validated).
// ---------------------------------------------------------------------------
__global__ void samp2_k(const float4* __restrict__ Twt, const int4* __restrict__ Tat,
                        const float* __restrict__ XTt, short* __restrict__ Sit,
                        const float4* __restrict__ Tws, const int4* __restrict__ Tas,
                        const float* __restrict__ XTs, short* __restrict__ Sis)
{
    int bx = blockIdx.x;
    const float4* Tw; const int4* Ta; const float* XT; short* Si;
    int N, NRND, nblk;
    if (bx < 4) { Tw = Twt; Ta = Tat; XT = XTt; Si = Sit; N = 256;  NRND = 256;  nblk = bx; }
    else        { Tw = Tws; Ta = Tas; XT = XTs; Si = Sis; N = 1024; NRND = 1024; nblk = bx - 4; }

    int tid = threadIdx.x;
    int g = tid >> 2, cc2 = tid & 3;
    int tap = blockIdx.y, b = blockIdx.z;
    int n = nblk * 64 + g;
    long ti = ((long)(b * 9 + tap)) * N + n;
    float4 w4 = Tw[ti];
    int4 a4 = Ta[ti];
    const float* Xb = XT + (long)b * 256 * N;
    const float4* r0 = (const float4*)(Xb + (long)a4.x * 256);
    const float4* r1 = (const float4*)(Xb + (long)a4.y * 256);
    const float4* r2 = (const float4*)(Xb + (long)a4.z * 256);
    const float4* r3 = (const float4*)(Xb + (long)a4.w * 256);
    long so = ((long)b * NRND + n) * 2304 + tap * 256;
    short4v out[16];
#pragma unroll
    for (int q = 0; q < 16; q++) {
        int i = q * 4 + cc2;
        float4 p = r0[i], qv = r1[i], s = r2[i], t = r3[i];
        out[q][0] = f2b(w4.x * p.x + w4.y * qv.x + w4.z * s.x + w4.w * t.x);
        out[q][1] = f2b(w4.x * p.y + w4.y * qv.y + w4.z * s.y + w4.w * t.y);
        out[q][2] = f2b(w4.x * p.z + w4.y * qv.z + w4.z * s.z + w4.w * t.z);
        out[q][3] = f2b(w4.x * p.w + w4.y * qv.w + w4.z * s.w + w4.w * t.w);
    }
#pragma unroll
    for (int q = 0; q < 16; q++)
        *(short4v*)&Si[so + q * 16 + cc2 * 4] = out[q];
}

// ---------------------------------------------------------------------------
// Deformable conv v11 (dcn9, r22, validated): fused template+search 1280-block
// dispatch, __launch_bounds__(256,4), 32-bit offsets, unroll 2.
// ---------------------------------------------------------------------------
__launch_bounds__(256, 4)
__global__ void dcn9_k(const short* __restrict__ Wh_s, const short* __restrict__ Si_s,
                       const short* __restrict__ Wh_t, const short* __restrict__ Si_t,
                       const float* __restrict__ bias_s, const float* __restrict__ bias_t,
                       float* __restrict__ Cs, float* __restrict__ Ct)
{
    __shared__ float red[8192];               // 2 slots x 64 fidx x 64 lanes

    int bid = blockIdx.x;
    const short* Wh; const short* Si; const float* bias; float* Cb;
    int N, mt, nt;
    if (bid < 1024) {                         // search: 16bz x 4mt x 16nt
        int bz = bid >> 6, t = bid & 63;
        mt = t >> 4; nt = t & 15;
        Wh = Wh_s; Si = Si_s + (long)bz * 1024 * 2304;
        bias = bias_s; Cb = Cs + (long)bz * 256 * 1024; N = 1024;
    } else {                                  // template: 16bz x 4mt x 4nt
        int r = bid - 1024;
        int bz = r >> 4, t = r & 15;
        mt = t >> 2; nt = t & 3;
        Wh = Wh_t; Si = Si_t + (long)bz * 256 * 2304;
        bias = bias_t; Cb = Ct + (long)bz * 256 * 256; N = 256;
    }
    const int m0 = mt * 64, n0 = nt * 64;

    const int tid = threadIdx.x;
    const int lane = tid & 63, wv = tid >> 6;
    const int lr = lane & 15, lq = lane >> 4;

    int aoff[4], boff[4];
#pragma unroll
    for (int mi = 0; mi < 4; mi++)
        aoff[mi] = (m0 + mi * 16 + lr) * 2304 + lq * 8;
#pragma unroll
    for (int ni = 0; ni < 4; ni++)
        boff[ni] = (n0 + ni * 16 + lr) * 2304 + lq * 8;

    f32x4 acc[4][4];
#pragma unroll
    for (int i = 0; i < 4; i++)
#pragma unroll
        for (int j = 0; j < 4; j++) acc[i][j] = (f32x4){0.f, 0.f, 0.f, 0.f};

    // ---- main loop: this wave's 18-kt K-chunk ----
    const int kbeg = wv * 18;
#pragma unroll 2
    for (int kt = kbeg; kt < kbeg + 18; kt++) {
        int koff = (kt >> 3) * 256 + (kt & 7) * 32;
        short8 ah[4], bh[4];
#pragma unroll
        for (int ni = 0; ni < 4; ni++)
            bh[ni] = *(const short8*)&Si[boff[ni] + koff];
#pragma unroll
        for (int mi = 0; mi < 4; mi++)
            ah[mi] = *(const short8*)&Wh[aoff[mi] + koff];
#pragma unroll
        for (int mi = 0; mi < 4; mi++)
#pragma unroll
            for (int ni = 0; ni < 4; ni++)
                acc[mi][ni] = __builtin_amdgcn_mfma_f32_16x16x32_bf16(ah[mi], bh[ni], acc[mi][ni], 0, 0, 0);
    }

    // ---- LDS tree reduction (lane-stride-4B layout: conflict-free b32) ----
    if (wv == 1 || wv == 3) {
        float* rp = &red[(wv == 1 ? 0 : 4096) + lane];
#pragma unroll
        for (int mi = 0; mi < 4; mi++)
#pragma unroll
            for (int ni = 0; ni < 4; ni++)
#pragma unroll
                for (int r2 = 0; r2 < 4; r2++)
                    rp[(mi * 16 + ni * 4 + r2) << 6] = acc[mi][ni][r2];
    }
    __syncthreads();
    if (wv == 0) {
        const float* rp = &red[lane];
#pragma unroll
        for (int mi = 0; mi < 4; mi++)
#pragma unroll
            for (int ni = 0; ni < 4; ni++)
#pragma unroll
                for (int r2 = 0; r2 < 4; r2++)
                    acc[mi][ni][r2] += rp[(mi * 16 + ni * 4 + r2) << 6];
    } else if (wv == 2) {
        float* rp = &red[4096 + lane];
#pragma unroll
        for (int mi = 0; mi < 4; mi++)
#pragma unroll
            for (int ni = 0; ni < 4; ni++)
#pragma unroll
                for (int r2 = 0; r2 < 4; r2++) {
                    int o = (mi * 16 + ni * 4 + r2) << 6;
                    float v = acc[mi][ni][r2] + rp[o];
                    rp[o] = v;
                }
    }
    __syncthreads();
    if (wv == 0) {
        const float* rp = &red[4096 + lane];
#pragma unroll
        for (int mi = 0; mi < 4; mi++)
#pragma unroll
            for (int ni = 0; ni < 4; ni++) {
                int col = n0 + ni * 16 + lr;
#pragma unroll
                for (int r2 = 0; r2 < 4; r2++) {
                    int row = m0 + mi * 16 + lq * 4 + r2;
                    float v = acc[mi][ni][r2] + rp[(mi * 16 + ni * 4 + r2) << 6];
                    Cb[(long)row * N + col] = v + bias[row];
                }
            }
    }
}

// Softmax over batch axis (16)
__global__ void softmax_b_k(float* __restrict__ att, long NN)
{
    long idx = (long)blockIdx.x * 256 + threadIdx.x;
    if (idx >= NN) return;
    float r[16];
    float mx = -1e30f;
#pragma unroll
    for (int b = 0; b < 16; b++) {
        r[b] = att[(long)b * NN + idx];
        mx = fmaxf(mx, r[b]);
    }
    float s = 0.f;
#pragma unroll
    for (int b = 0; b < 16; b++) { r[b] = expf(r[b] - mx); s += r[b]; }
    float inv = 1.f / s;
#pragma unroll
    for (int b = 0; b < 16; b++) att[(long)b * NN + idx] = r[b] * inv;
}

// ---------------------------------------------------------------------------
// gram_sm2_k (r25): M[b][c][d] = softmax_c(gram_t) + softmax_c(gram_s).
// r15 diagnosis: old version ran 4096 threads total (16 waves machine-wide)
// with 3 serial 256-load passes — pure latency exposure.  Now 256 blocks x
// 256 threads: 16 d's/block, 16 c-groups of 16 per d, LDS tree for max and
// sum.  Partial-sum regrouping only (256 positive terms) — error ~1e-6.
// Grid (B, 16), blk 256.
// ---------------------------------------------------------------------------
__global__ void gram_sm2_k(const float* __restrict__ gt, const float* __restrict__ gs,
                           float* __restrict__ Mo)
{
    __shared__ float red[2][17][16];
    int b = blockIdx.x;
    int td = threadIdx.x & 15;
    int tc = threadIdx.x >> 4;                // 0..15
    int d = blockIdx.y * 16 + td;
    const float* gtb = gt + (long)b * 65536;
    const float* gsb = gs + (long)b * 65536;
    float* mb = Mo + (long)b * 65536;

    // pass 1: max over c
    float mt = -1e30f, ms = -1e30f;
    for (int c = tc * 16; c < tc * 16 + 16; c++) {
        mt = fmaxf(mt, gtb[c * 256 + d]);
        ms = fmaxf(ms, gsb[c * 256 + d]);
    }
    red[0][tc][td] = mt;
    red[1][tc][td] = ms;
    __syncthreads();
    if (tc == 0) {
        float a = -1e30f, bb = -1e30f;
        for (int i = 0; i < 16; i++) {
            a = fmaxf(a, red[0][i][td]);
            bb = fmaxf(bb, red[1][i][td]);
        }
        red[0][16][td] = a;
        red[1][16][td] = bb;
    }
    __syncthreads();
    mt = red[0][16][td];
    ms = red[1][16][td];
    __syncthreads();

    // pass 2: sum of exp
    float st = 0.f, ss = 0.f;
    for (int c = tc * 16; c < tc * 16 + 16; c++) {
        st += expf(gtb[c * 256 + d] - mt);
        ss += expf(gsb[c * 256 + d] - ms);
    }
    red[0][tc][td] = st;
    red[1][tc][td] = ss;
    __syncthreads();
    if (tc == 0) {
        float a = 0.f, bb = 0.f;
        for (int i = 0; i < 16; i++) {
            a += red[0][i][td];
            bb += red[1][i][td];
        }
        red[0][16][td] = a;
        red[1][16][td] = bb;
    }
    __syncthreads();
    float it = 1.f / red[0][16][td];
    float is = 1.f / red[1][16][td];

    // pass 3: write
    for (int c = tc * 16; c < tc * 16 + 16; c++)
        mb[c * 256 + d] = expf(gtb[c * 256 + d] - mt) * it +
                          expf(gsb[c * 256 + d] - ms) * is;
}

__global__ void cast_out_k(const float* __restrict__ t, const float* __restrict__ s,
                           void* __restrict__ out, long nt, long ntot,
                           const int* __restrict__ flag)
{
    long idx = (long)blockIdx.x * 256 + threadIdx.x;
    if (idx >= ntot) return;
    float v = (idx < nt) ? t[idx] : s[idx - nt];
    if (*flag) ((float*)out)[idx] = v;
    else       ((bf16*)out)[idx] = __float2bfloat16(v);
}

// ---------------------------------------------------------------------------
extern "C" void kernel_launch(void* const* d_in, const int* in_sizes, int n_in,
                              void* d_out, int out_size, void* d_ws, size_t ws_size,
                              hipStream_t stream)
{
    const int B = 16, C = 256;
    const int Nt = 256, Ns = 1024;
    const long sXt = (long)C * Nt, sXs = (long)C * Ns;
    dim3 blk(256);

    float* ws = (float*)d_ws;
    int* flag = (int*)d_ws;
    long off = 16;
    auto alloc = [&](long n) { float* p = ws + off; off += n; return p; };

    float* xt32     = alloc((long)B * C * Nt);
    float* xs32     = alloc((long)B * C * Ns);   // -> out_s_f32
    float* Wf       = alloc(1470464);
    // r25: merged qkv buffers — rows 0-31 q, 32-63 k, 64-319 v, per-b
    // stride 320*N.  Same total size as the old q/k/v allocations.
    float* qkv_t    = alloc((long)B * 320 * Nt);
    float* qkv_s    = alloc((long)B * 320 * Ns); // -> DCN prep region late
    float* Wqkv_t   = alloc(81920);
    float* bqkv_t   = alloc(320);
    float* Wqkv_s   = alloc(81920);
    float* bqkv_s   = alloc(320);
    float* gram_t   = alloc((long)B * C * C);    // -> out_t_f32
    float* gram_s   = alloc((long)B * C * C);
    float* Mc       = alloc((long)B * C * C);
    float* att_t    = alloc((long)B * Nt * Nt);  // xtT early / atT late
    float* att_slab = alloc((long)B * Ns * 256); // xsT early / asrT late
    float* at       = alloc((long)B * C * Nt);   // -> Si_t region late
    float* asr      = alloc((long)B * C * Ns);   // -> Si_t region late
    float* oo_t     = alloc((long)B * 27 * Nt);
    float* oo_s     = alloc((long)B * 27 * Ns);
    // Si region: full fp32 att (16.78M floats) during step 7, search Si later.
    float* Si_f     = alloc(18874368);
    short* Si = (short*)Si_f;
    float* att_full = Si_f;

    float* out_t_f32 = gram_t;
    float* out_s_f32 = xs32;
    float* xtT       = att_t;
    float* xsT       = att_slab;
    float* atT       = att_t;     // reuse after attention phases complete
    float* asrT      = att_slab;  // reuse after attention phases complete
    // Template Si lives in the dead at+asr region (needs 4.72M floats < 5.24M).
    short* Si_t = (short*)at;
    // DCN prep region lives in qkv_s (dead after step 7 PV; needs 2.66M < 5.24M).
    short* Wi_t = (short*)qkv_s;                 // 589824 shorts each (hi-only)
    short* Wi_s = (short*)qkv_s + 589824;
    float* tb   = qkv_s + 1179648;
    float4* Tw_t = (float4*)tb;
    int4*   Ta_t = (int4*)(tb + 147456);
    float4* Tw_s = (float4*)(tb + 2 * 147456);
    int4*   Ta_s = (int4*)(tb + 2 * 147456 + 589824);

    // ---- 0) detect + ingest (r25: weights scattered into packed Wqkv) ----
    detect_k<<<dim3(1), blk, 0, stream>>>((const unsigned short*)d_in[0], flag);
    long woff[22];
    {
        long acc = 0;
        for (int i = 2; i < 22; i++) { woff[i] = acc; acc += (in_sizes[i] + 7) & ~7L; }
    }
    float* wdst[22];
    for (int i = 2; i < 22; i++) wdst[i] = Wf + woff[i];
    wdst[2]  = Wqkv_t;          wdst[3]  = bqkv_t;
    wdst[4]  = Wqkv_t + 8192;   wdst[5]  = bqkv_t + 32;
    wdst[6]  = Wqkv_t + 16384;  wdst[7]  = bqkv_t + 64;
    wdst[8]  = Wqkv_s;          wdst[9]  = bqkv_s;
    wdst[10] = Wqkv_s + 8192;   wdst[11] = bqkv_s + 32;
    wdst[12] = Wqkv_s + 16384;  wdst[13] = bqkv_s + 64;
    IArgs ia;
    long tot = 0;
    auto seg = [&](int s, const void* src, float* dst, long n) {
        ia.src[s] = src; ia.dst[s] = dst; ia.start[s] = tot; tot += n;
    };
    seg(0, d_in[0], xt32, (long)B * C * Nt);
    seg(1, d_in[0], at,   (long)B * C * Nt);
    seg(2, d_in[1], xs32, (long)B * C * Ns);
    seg(3, d_in[1], asr,  (long)B * C * Ns);
    for (int i = 2; i < 22; i++) seg(2 + i, d_in[i], wdst[i], in_sizes[i]);
    ia.start[NSEG] = tot;
    ingest_all_k<<<dim3((unsigned)((tot + 255) / 256)), blk, 0, stream>>>(ia, flag);

    const float *t_off_w = Wf + woff[14], *t_off_b = Wf + woff[15];
    const float *t_dcn_w = Wf + woff[16], *t_dcn_b = Wf + woff[17];
    const float *s_off_w = Wf + woff[18], *s_off_b = Wf + woff[19];
    const float *s_dcn_w = Wf + woff[20], *s_dcn_b = Wf + woff[21];

    // ---- 1) transposes (merged) + prefills (merged) ----
    tr2_k<<<dim3((Nt + Ns) / 32, 8, B), dim3(32, 8), 0, stream>>>(
        xt32, xtT, Nt, xs32, xsT, Ns);
    fill_k<<<dim3((2 * B * C * C) / 256), blk, 0, stream>>>(gram_t, nullptr, 1, 1, 2L * B * C * C);
    fillo_k<<<dim3((unsigned)((B * 27L * (Nt + Ns) + 255) / 256)), blk, 0, stream>>>(
        oo_t, t_off_b, Nt, (long)B * 27 * Nt,
        oo_s, s_off_b, Ns, (long)B * 27 * Ns);

    // ---- 2) merged qkv projections (r25): ONE M=320 GEMM per side ----
    mgemm<false, 1, false, true, 2, 1><<<dim3(Nt / 64, 5, B), blk, 0, stream>>>(
        Wqkv_t, 256, 1, 0, xtT, 256, sXt, qkv_t, Nt, (long)320 * Nt, bqkv_t, 320, Nt, 256, 0, 0);
    mgemm<false, 1, false, true, 2, 1><<<dim3(Ns / 64, 5, B), blk, 0, stream>>>(
        Wqkv_s, 256, 1, 0, xsT, 256, sXs, qkv_s, Ns, (long)320 * Ns, bqkv_s, 320, Ns, 256, 0, 0);

    // ---- 3) gram matrices (BMODE1, K-split 4, PREC1 — validated since r0) ----
    mgemm<false, 1, false, false, 1, 4><<<dim3(4, 16, B), blk, 0, stream>>>(
        xt32, Nt, 1, sXt, xt32, Nt, sXt, gram_t, 256, (long)C * C, nullptr, 256, 256, Nt, 0, 0);
    mgemm<false, 1, false, false, 1, 4><<<dim3(4, 16, B), blk, 0, stream>>>(
        xs32, Ns, 1, sXs, xs32, Ns, sXs, gram_s, 256, (long)C * C, nullptr, 256, 256, Ns, 0, 0);

    // ---- 4) M (parallelized r25) ----
    gram_sm2_k<<<dim3(B, 16), blk, 0, stream>>>(gram_t, gram_s, Mc);

    // ---- 5) channel attention (B = x^T, BMODE1, PREC2) ----
    mgemm<false, 1, true, false, 2, 2><<<dim3(Nt / 64, 8, B), blk, 0, stream>>>(
        Mc, 256, 1, (long)C * C, xtT, 256, sXt, at, Nt, sXt, nullptr, 256, Nt, 256, 0, 0);
    mgemm<false, 1, true, false, 2, 1><<<dim3(Ns / 64, 4, B), blk, 0, stream>>>(
        Mc, 256, 1, (long)C * C, xsT, 256, sXs, asr, Ns, sXs, nullptr, 256, Ns, 256, 0, 0);

    // ---- 6) template spatial attention (PREC2; q/k/v are qkv_t views) ----
    mgemm<true, 0, false, false, 2, 1><<<dim3(4, 4, B), blk, 0, stream>>>(
        qkv_t + 32 * Nt, Nt, 1, (long)320 * Nt, qkv_t, Nt, (long)320 * Nt,
        att_t, Nt, (long)Nt * Nt, nullptr, Nt, Nt, 32, 0, 0);
    softmax_b_k<<<dim3((Nt * Nt) / 256), blk, 0, stream>>>(att_t, (long)Nt * Nt);
    mgemm<false, 1, true, false, 2, 2><<<dim3(Nt / 64, 8, B), blk, 0, stream>>>(
        qkv_t + 64 * Nt, Nt, 1, (long)320 * Nt, att_t, Nt, (long)Nt * Nt,
        at, Nt, sXt, nullptr, 256, Nt, Nt, 0, 0);

    // ---- 7) search spatial attention — FULL WIDTH (r23, validated) ----
    mgemm<true, 0, false, false, 2, 1><<<dim3(Ns / 64, Ns / 64, B), blk, 0, stream>>>(
        qkv_s + 32 * Ns, Ns, 1, (long)320 * Ns, qkv_s, Ns, (long)320 * Ns,
        att_full, Ns, (long)Ns * Ns, nullptr, Ns, Ns, 32, 0, 0);
    softmax_b_k<<<dim3((unsigned)(((long)Ns * Ns) / 256)), blk, 0, stream>>>(
        att_full, (long)Ns * Ns);
    mgemm<false, 1, true, false, 2, 1><<<dim3(Ns / 64, 4, B), blk, 0, stream>>>(
        qkv_s + 64 * Ns, Ns, 1, (long)320 * Ns, att_full, Ns, (long)Ns * Ns,
        asr, Ns, sXs, nullptr, 256, Ns, Ns, 0, 0);

    // ---- 8) offset convs (im2col, K-split 4, PREC2) ----
    mgemm<false, 3, false, false, 2, 4><<<dim3(Nt / 64, 4, B), blk, 0, stream>>>(
        t_off_w, 2304, 1, 0, at, Nt, sXt, oo_t, Nt, (long)27 * Nt,
        nullptr, 27, Nt, 2304, 16, 4);
    mgemm<false, 3, false, false, 2, 4><<<dim3(Ns / 64, 4, B), blk, 0, stream>>>(
        s_off_w, 2304, 1, 0, asr, Ns, sXs, oo_s, Ns, (long)27 * Ns,
        nullptr, 27, Ns, 2304, 32, 5);

    // ---- 9) DCN prep (merged dispatches; qkv_s region now dead) ----
    wre5_k<<<dim3(4608), blk, 0, stream>>>(t_dcn_w, Wi_t, s_dcn_w, Wi_s);
    dcnw2_k<<<dim3((unsigned)((16L * 9 * (Nt + Ns)) / 256)), blk, 0, stream>>>(
        oo_t, Tw_t, Ta_t, oo_s, Tw_s, Ta_s);
    // transpose attention outputs to [n][c] for channel-contiguous sampling
    tr2_k<<<dim3((Nt + Ns) / 32, 8, B), dim3(32, 8), 0, stream>>>(
        at, atT, Nt, asr, asrT, Ns);

    // ---- 10) deformable convs: merged sampler + ONE fused 1280-block GEMM ----
    samp2_k<<<dim3(20, 9, B), blk, 0, stream>>>(
        Tw_t, Ta_t, atT, Si_t, Tw_s, Ta_s, asrT, Si);
    dcn9_k<<<dim3(1280), blk, 0, stream>>>(Wi_s, Si, Wi_t, Si_t,
                                           s_dcn_b, t_dcn_b, out_s_f32, out_t_f32);

    // ---- 11) emit output ----
    long nt = (long)B * C * Nt;
    long ntot = nt + (long)B * C * Ns;
    cast_out_k<<<dim3((unsigned)((ntot + 255) / 256)), blk, 0, stream>>>(
        out_t_f32, out_s_f32, d_out, nt, ntot, flag);
}